// Round 4
// baseline (5317.182 us; speedup 1.0000x reference)
//
#include <hip/hip_runtime.h>
#include <cmath>

// RouterCond fused, round 4: round-3 structure + corrected launch_bounds.
// __launch_bounds__ 2nd arg behaves as min BLOCKS/CU (CUDA semantics) on this
// hipcc: (512,4) forced VGPR=64 -> spill collapse (round 3). (512,2) -> cap 128.
#define N_TOK 32768
#define D0    1024
#define DCC   512
#define DIN   1536
#define JD    3072
#define NE    64
#define BM    64           // tokens per block (512 blocks -> 2 blocks/CU)
#define BJ    256          // j-chunk
#define KC    32           // k-step
#define NJC   (JD/BJ)      // 12
#define NKS   (DIN/KC)     // 48
#define NTH   512
#define ALD   36           // A1 row stride in halves (18 dwords % 32 -> 2-way, free)
#define BLD   36
#define HLD   68           // H row stride in halves
#define NSL   4            // GEMM2 j-slices per jc
#define EPSV  1e-9f

typedef _Float16 half8  __attribute__((ext_vector_type(8)));
typedef _Float16 half4v __attribute__((ext_vector_type(4)));
typedef float    f32x4  __attribute__((ext_vector_type(4)));

// LDS byte offsets (total 65024 B -> 2 blocks/CU on 160 KiB)
#define OFF_A1H 0
#define OFF_A1L (OFF_A1H + BM*ALD*2)      // 4608
#define OFF_B1H (OFF_A1L + BM*ALD*2)      // 9216
#define OFF_B1L (OFF_B1H + BJ*BLD*2)      // 27648
#define OFF_H   (OFF_B1L + BJ*BLD*2)      // 46080
#define OFF_HL  (OFF_H   + BM*HLD*2)      // 54784
#define OFF_EPI (OFF_HL  + BM*HLD*2)      // 63488
#define LDS_TOTAL (OFF_EPI + 6*BM*4)      // 65024
#define OFF_LRED OFF_H                     // [64][68] f32, aliases dead H

__device__ __forceinline__ f32x4 mfma16(half8 a, half8 b, f32x4 c) {
    return __builtin_amdgcn_mfma_f32_16x16x32_f16(a, b, c, 0, 0, 0);
}

__device__ __forceinline__ void split4(const float4 v, half4v& hh, half4v& hl) {
    float f[4] = {v.x, v.y, v.z, v.w};
    #pragma unroll
    for (int i = 0; i < 4; ++i) {
        _Float16 h = (_Float16)f[i];
        hh[i] = h;
        hl[i] = (_Float16)(f[i] - (float)h);
    }
}

__device__ __forceinline__ void split8(const float4 v0, const float4 v1, half8& hh, half8& hl) {
    float f[8] = {v0.x, v0.y, v0.z, v0.w, v1.x, v1.y, v1.z, v1.w};
    #pragma unroll
    for (int i = 0; i < 8; ++i) {
        _Float16 h = (_Float16)f[i];
        hh[i] = h;
        hl[i] = (_Float16)(f[i] - (float)h);
    }
}

__global__ __launch_bounds__(NTH, 2)
void router_v4(const float* __restrict__ inp, const float* __restrict__ cnd,
               const float* __restrict__ W1, const float* __restrict__ W2,
               float* __restrict__ out_mask, float* __restrict__ out_topi,
               float* __restrict__ out_rp, float* __restrict__ out_probs)
{
    __shared__ __align__(16) char smem[LDS_TOTAL];
    _Float16* const A1h = (_Float16*)(smem + OFF_A1H);
    _Float16* const A1l = (_Float16*)(smem + OFF_A1L);
    _Float16* const B1h = (_Float16*)(smem + OFF_B1H);
    _Float16* const B1l = (_Float16*)(smem + OFF_B1L);
    _Float16* const Hh  = (_Float16*)(smem + OFF_H);
    _Float16* const Hl  = (_Float16*)(smem + OFF_HL);

    const int tid  = threadIdx.x;
    const int lane = tid & 63;
    const int w    = tid >> 6;      // wave 0..7
    const int tg   = w >> 2;        // token half: rows tg*32..+31
    const int jg   = w & 3;         // j quarter / expert group
    const int l15  = lane & 15;
    const int lg   = lane >> 4;     // 0..3
    const int t0   = blockIdx.x * BM;

    const int arow = tid >> 3, ak4  = (tid & 7) * 4;
    const int brow = tid >> 1, bk16 = (tid & 1) * 16;

    int aoff[2], boff[4];
    #pragma unroll
    for (int tf = 0; tf < 2; ++tf) aoff[tf] = (tg*32 + tf*16 + l15) * ALD + lg*8;
    #pragma unroll
    for (int jf = 0; jf < 4; ++jf) boff[jf] = (jg*64 + jf*16 + l15) * BLD + lg*8;

    const f32x4 vzero = {0.f, 0.f, 0.f, 0.f};
    f32x4 lacc[2] = {vzero, vzero};

    const float* const xA = inp + (size_t)(t0 + arow) * D0;
    const float* const xC = cnd + (size_t)(t0 + arow) * DCC;

    for (int jc = 0; jc < NJC; ++jc) {
        const float* const w1r = W1 + (size_t)(jc*BJ + brow) * DIN;

        f32x4 acc1[2][4];
        #pragma unroll
        for (int tf = 0; tf < 2; ++tf)
            #pragma unroll
            for (int jf = 0; jf < 4; ++jf) acc1[tf][jf] = vzero;

        float4 ra  = *(const float4*)(xA + ak4);
        float4 rb0 = *(const float4*)(w1r + bk16);
        float4 rb1 = *(const float4*)(w1r + bk16 + 4);
        float4 rb2 = *(const float4*)(w1r + bk16 + 8);
        float4 rb3 = *(const float4*)(w1r + bk16 + 12);
        {
            half4v h4, l4;
            split4(ra, h4, l4);
            *(half4v*)(A1h + arow*ALD + ak4) = h4;
            *(half4v*)(A1l + arow*ALD + ak4) = l4;
            half8 h8, l8;
            split8(rb0, rb1, h8, l8);
            *(half8*)(B1h + brow*BLD + bk16) = h8;
            *(half8*)(B1l + brow*BLD + bk16) = l8;
            split8(rb2, rb3, h8, l8);
            *(half8*)(B1h + brow*BLD + bk16 + 8) = h8;
            *(half8*)(B1l + brow*BLD + bk16 + 8) = l8;
        }
        __syncthreads();

        for (int ks = 0; ks < NKS; ++ks) {
            const bool more = (ks + 1 < NKS);
            if (more) {
                const int k = (ks + 1) * KC;
                const float* sA = (k + ak4 < D0) ? (xA + k + ak4) : (xC + k + ak4 - D0);
                ra  = *(const float4*)sA;
                rb0 = *(const float4*)(w1r + k + bk16);
                rb1 = *(const float4*)(w1r + k + bk16 + 4);
                rb2 = *(const float4*)(w1r + k + bk16 + 8);
                rb3 = *(const float4*)(w1r + k + bk16 + 12);
            }
            half8 ah[2], al[2], bh[4], bl[4];
            #pragma unroll
            for (int tf = 0; tf < 2; ++tf) {
                ah[tf] = *(const half8*)(A1h + aoff[tf]);
                al[tf] = *(const half8*)(A1l + aoff[tf]);
            }
            #pragma unroll
            for (int jf = 0; jf < 4; ++jf) {
                bh[jf] = *(const half8*)(B1h + boff[jf]);
                bl[jf] = *(const half8*)(B1l + boff[jf]);
            }
            #pragma unroll
            for (int tf = 0; tf < 2; ++tf)
                #pragma unroll
                for (int jf = 0; jf < 4; ++jf) {
                    acc1[tf][jf] = mfma16(ah[tf], bh[jf], acc1[tf][jf]);
                    acc1[tf][jf] = mfma16(ah[tf], bl[jf], acc1[tf][jf]);
                    acc1[tf][jf] = mfma16(al[tf], bh[jf], acc1[tf][jf]);
                }
            __syncthreads();
            if (more) {
                half4v h4, l4;
                split4(ra, h4, l4);
                *(half4v*)(A1h + arow*ALD + ak4) = h4;
                *(half4v*)(A1l + arow*ALD + ak4) = l4;
                half8 h8, l8;
                split8(rb0, rb1, h8, l8);
                *(half8*)(B1h + brow*BLD + bk16) = h8;
                *(half8*)(B1l + brow*BLD + bk16) = l8;
                split8(rb2, rb3, h8, l8);
                *(half8*)(B1h + brow*BLD + bk16 + 8) = h8;
                *(half8*)(B1l + brow*BLD + bk16 + 8) = l8;
                __syncthreads();
            }
        }

        // GEMM2 in 4 j-slices of 64; W2 frags straight from global (L2-resident)
        const float* const w2p = W2 + (size_t)(jg*16 + l15) * JD + jc*BJ;
        #pragma unroll
        for (int s = 0; s < NSL; ++s) {
            float4 wq0 = *(const float4*)(w2p + s*64 + lg*8);
            float4 wq1 = *(const float4*)(w2p + s*64 + lg*8 + 4);
            float4 wq2 = *(const float4*)(w2p + s*64 + 32 + lg*8);
            float4 wq3 = *(const float4*)(w2p + s*64 + 32 + lg*8 + 4);

            if (jg == s) {
                #pragma unroll
                for (int tf = 0; tf < 2; ++tf)
                    #pragma unroll
                    for (int jf = 0; jf < 4; ++jf)
                        #pragma unroll
                        for (int r = 0; r < 4; ++r) {
                            const float v = acc1[tf][jf][r];
                            const float g = 0.5f * v * (1.0f + erff(v * 0.70710678118654752f));
                            const _Float16 gh = (_Float16)g;
                            const _Float16 gl = (_Float16)(g - (float)gh);
                            const int o = (tg*32 + tf*16 + lg*4 + r) * HLD + jf*16 + l15;
                            Hh[o] = gh; Hl[o] = gl;
                        }
            }
            __syncthreads();
            #pragma unroll
            for (int ks2 = 0; ks2 < 2; ++ks2) {
                half8 b2h, b2l;
                split8(ks2 ? wq2 : wq0, ks2 ? wq3 : wq1, b2h, b2l);
                #pragma unroll
                for (int tf = 0; tf < 2; ++tf) {
                    const int o = (tg*32 + tf*16 + l15) * HLD + ks2*32 + lg*8;
                    half8 a2h = *(const half8*)(Hh + o);
                    half8 a2l = *(const half8*)(Hl + o);
                    lacc[tf] = mfma16(a2h, b2h, lacc[tf]);
                    lacc[tf] = mfma16(a2h, b2l, lacc[tf]);
                    lacc[tf] = mfma16(a2l, b2h, lacc[tf]);
                }
            }
            __syncthreads();
        }
    }

    // epilogue: gather logits, softmax + top-2, write outputs
    float* const Lred = (float*)(smem + OFF_LRED);
    #pragma unroll
    for (int tf = 0; tf < 2; ++tf)
        #pragma unroll
        for (int r = 0; r < 4; ++r)
            Lred[(tg*32 + tf*16 + lg*4 + r) * HLD + jg*16 + l15] = lacc[tf][r];
    __syncthreads();

    float* const mA   = (float*)(smem + OFF_EPI);
    float* const invA = mA + BM;
    int*   const i1A  = (int*)(invA + BM);
    int*   const i2A  = i1A + BM;
    float* const rp1A = (float*)(i2A + BM);
    float* const rp2A = rp1A + BM;

    if (tid < BM) {
        const float* row = Lred + tid * HLD;
        float m = -3.402823466e38f;
        for (int e = 0; e < NE; ++e) m = fmaxf(m, row[e]);
        float s = 0.f, v1 = -3.402823466e38f, v2 = -3.402823466e38f;
        int i1 = 0, i2 = 0;
        for (int e = 0; e < NE; ++e) {
            const float v = row[e];
            s += expf(v - m);
            if (v > v1)      { v2 = v1; i2 = i1; v1 = v; i1 = e; }
            else if (v > v2) { v2 = v; i2 = e; }
        }
        const float inv = 1.f / s;
        const float p1 = fminf(expf(v1 - m) * inv + EPSV, 1.f - EPSV);
        const float p2 = fminf(expf(v2 - m) * inv + EPSV, 1.f - EPSV);
        mA[tid] = m; invA[tid] = inv; i1A[tid] = i1; i2A[tid] = i2;
        const float den = p1 + p2;
        rp1A[tid] = p1 / den; rp2A[tid] = p2 / den;
    }
    __syncthreads();

    for (int idx = tid; idx < BM * NE; idx += NTH) {
        const int r = idx >> 6, e = idx & 63;
        const size_t o = (size_t)(t0 + r) * NE + e;
        const float p = fminf(expf(Lred[r * HLD + e] - mA[r]) * invA[r] + EPSV, 1.f - EPSV);
        const int b1 = (e == i1A[r]), b2 = (e == i2A[r]);
        out_probs[o] = p;
        out_mask[o]  = (b1 | b2) ? 1.f : 0.f;
        out_rp[o]    = b1 ? rp1A[r] : (b2 ? rp2A[r] : 0.f);
    }
    if (tid < BM * 2) {
        const int r = tid >> 1, q = tid & 1;
        out_topi[(size_t)(t0 + r) * 2 + q] = (float)(q ? i2A[r] : i1A[r]);
    }
}

extern "C" void kernel_launch(void* const* d_in, const int* in_sizes, int n_in,
                              void* d_out, int out_size, void* d_ws, size_t ws_size,
                              hipStream_t stream) {
    const float* inp = (const float*)d_in[0];
    const float* cnd = (const float*)d_in[1];
    const float* W1  = (const float*)d_in[2];
    const float* W2  = (const float*)d_in[3];

    float* out = (float*)d_out;
    const size_t NT = (size_t)N_TOK;
    float* out_mask  = out;
    float* out_topi  = out + NT * NE;
    float* out_rp    = out + NT * NE + NT * 2;
    float* out_probs = out + NT * NE + NT * 2 + NT * NE;

    dim3 grid(N_TOK / BM);   // 512 blocks -> 2 per CU
    dim3 block(NTH);
    hipLaunchKernelGGL(router_v4, grid, block, 0, stream,
                       inp, cnd, W1, W2, out_mask, out_topi, out_rp, out_probs);
}

// Round 5
// 1407.819 us; speedup vs baseline: 3.7769x; 3.7769x over previous
//
#include <hip/hip_runtime.h>
#include <cmath>

// RouterCond fused, round 5: round-2 geometry (BM=128,BJ=128,KC=32, 256 blocks)
// + single-barrier double-buffered k-loop + pre-split fp16 hi/lo W1/W2 in d_ws
// + padded conflict-free LDS + barrier-free GEMM2 (wave-private H tiles).
#define N_TOK 32768
#define D0    1024
#define DCC   512
#define DIN   1536
#define JD    3072
#define NE    64
#define BM    128
#define BJ    128
#define KC    32
#define NJC   (JD/BJ)      // 24
#define NKS   (DIN/KC)     // 48
#define NTH   512
#define ALD   40           // A/B tile row stride in halves (20 dw %32 -> 2-way, free)
#define HLD   136          // H row stride in halves (68 dw %32=4 -> 2-way, free)
#define EPSV  1e-9f

typedef _Float16 half8 __attribute__((ext_vector_type(8)));
typedef float    f32x4 __attribute__((ext_vector_type(4)));

// ---- LDS layout (bytes). Total 154624 <= 160 KiB -> 1 block/CU.
#define SZ_AB   (BM*ALD*2)            // 10240 per plane per buffer
#define OFF_A   0                      // [buf][plane]: buf*2*SZ_AB + plane*SZ_AB
#define OFF_B   (4*SZ_AB)             // 40960
#define OFF_HH  (8*SZ_AB)             // 81920
#define OFF_HL  (OFF_HH + BM*HLD*2)   // 116736
#define OFF_EPI (OFF_HL + BM*HLD*2)   // 151552
#define LDS_TOTAL (OFF_EPI + 6*BM*4)  // 154624
#define OFF_LRED OFF_HH               // [128][68] f32 = 34816, aliases dead H

// ---- workspace layout (halves)
#define W1_N   (JD*DIN)               // 4718592
#define W2_N   (NE*JD)                // 196608
#define WS_REQ ((size_t)(W1_N + W2_N) * 2 * 2)   // 19,660,800 bytes

__device__ __forceinline__ f32x4 mfma16(half8 a, half8 b, f32x4 c) {
    return __builtin_amdgcn_mfma_f32_16x16x32_f16(a, b, c, 0, 0, 0);
}

__device__ __forceinline__ void split8(const float4 v0, const float4 v1, half8& hh, half8& hl) {
    float f[8] = {v0.x, v0.y, v0.z, v0.w, v1.x, v1.y, v1.z, v1.w};
    #pragma unroll
    for (int i = 0; i < 8; ++i) {
        _Float16 h = (_Float16)f[i];
        hh[i] = h;
        hl[i] = (_Float16)(f[i] - (float)h);
    }
}

// -------- prologue: split fp32 weights into fp16 hi/lo planes --------
__global__ void presplit(const float* __restrict__ src, _Float16* __restrict__ hi,
                         _Float16* __restrict__ lo, int n4) {
    typedef _Float16 half4v __attribute__((ext_vector_type(4)));
    int i = blockIdx.x * blockDim.x + threadIdx.x;
    const int stride = gridDim.x * blockDim.x;
    for (; i < n4; i += stride) {
        float4 v = *(const float4*)(src + (size_t)i * 4);
        half4v h, l;
        float f[4] = {v.x, v.y, v.z, v.w};
        #pragma unroll
        for (int q = 0; q < 4; ++q) {
            _Float16 hh = (_Float16)f[q];
            h[q] = hh;
            l[q] = (_Float16)(f[q] - (float)hh);
        }
        *(half4v*)(hi + (size_t)i * 4) = h;
        *(half4v*)(lo + (size_t)i * 4) = l;
    }
}

// -------- main fused kernel --------
__global__ __launch_bounds__(NTH, 1)
void router_v5(const float* __restrict__ inp, const float* __restrict__ cnd,
               const _Float16* __restrict__ W1h, const _Float16* __restrict__ W1l,
               const _Float16* __restrict__ W2h, const _Float16* __restrict__ W2l,
               float* __restrict__ out_mask, float* __restrict__ out_topi,
               float* __restrict__ out_rp, float* __restrict__ out_probs)
{
    __shared__ __align__(16) char smem[LDS_TOTAL];
    _Float16* const Hh = (_Float16*)(smem + OFF_HH);
    _Float16* const Hl = (_Float16*)(smem + OFF_HL);

    const int tid  = threadIdx.x;
    const int lane = tid & 63;
    const int w    = tid >> 6;      // wave 0..7
    const int tg   = w >> 1;        // token group: rows tg*32..+31
    const int jg   = w & 1;         // j half: cols jg*64..+63
    const int l15  = lane & 15;
    const int lg   = lane >> 4;     // 0..3
    const int t0   = blockIdx.x * BM;

    // staging: 512 threads cover 128 rows x 32 k (8 elems each)
    const int srow = tid >> 2;          // 0..127
    const int sk8  = (tid & 3) * 8;     // 0,8,16,24
    const int soff = srow * ALD + sk8;  // halves, within a plane

    int aoff[2], boff[4];
    #pragma unroll
    for (int tf = 0; tf < 2; ++tf) aoff[tf] = (tg*32 + tf*16 + l15) * ALD + lg*8;
    #pragma unroll
    for (int jf = 0; jf < 4; ++jf) boff[jf] = (jg*64 + jf*16 + l15) * ALD + lg*8;

    const f32x4 vzero = {0.f, 0.f, 0.f, 0.f};
    f32x4 lacc[2][4];                    // [tf][ef] logits, partial over jg
    #pragma unroll
    for (int tf = 0; tf < 2; ++tf)
        #pragma unroll
        for (int ef = 0; ef < 4; ++ef) lacc[tf][ef] = vzero;

    const float* const xA = inp + (size_t)(t0 + srow) * D0;
    const float* const xC = cnd + (size_t)(t0 + srow) * DCC;

    for (int jc = 0; jc < NJC; ++jc) {
        const _Float16* const w1hr = W1h + (size_t)(jc*BJ + srow) * DIN;
        const _Float16* const w1lr = W1l + (size_t)(jc*BJ + srow) * DIN;

        f32x4 acc1[2][4];
        #pragma unroll
        for (int tf = 0; tf < 2; ++tf)
            #pragma unroll
            for (int jf = 0; jf < 4; ++jf) acc1[tf][jf] = vzero;

        int cur = 0;
        // prologue: stage k-step 0 (k<1024 -> inp side)
        {
            float4 ra0 = *(const float4*)(xA + sk8);
            float4 ra1 = *(const float4*)(xA + sk8 + 4);
            half8 rbh = *(const half8*)(w1hr + sk8);
            half8 rbl = *(const half8*)(w1lr + sk8);
            _Float16* Ah = (_Float16*)(smem + OFF_A);
            _Float16* Al = (_Float16*)(smem + OFF_A + SZ_AB);
            _Float16* Bh = (_Float16*)(smem + OFF_B);
            _Float16* Bl = (_Float16*)(smem + OFF_B + SZ_AB);
            half8 hh, hl;
            split8(ra0, ra1, hh, hl);
            *(half8*)(Ah + soff) = hh; *(half8*)(Al + soff) = hl;
            *(half8*)(Bh + soff) = rbh; *(half8*)(Bl + soff) = rbl;
        }
        __syncthreads();

        for (int ks = 0; ks < NKS; ++ks) {
            const bool more = (ks + 1 < NKS);
            float4 ra0, ra1; half8 rbh, rbl;
            if (more) {                      // prefetch next k-step into regs
                const int k = (ks + 1) * KC + sk8;
                const float* sA = (k < D0) ? (xA + k) : (xC + k - D0);
                ra0 = *(const float4*)sA;
                ra1 = *(const float4*)(sA + 4);
                rbh = *(const half8*)(w1hr + k);
                rbl = *(const half8*)(w1lr + k);
            }
            const _Float16* Ah = (const _Float16*)(smem + OFF_A + cur*(2*SZ_AB));
            const _Float16* Al = (const _Float16*)(smem + OFF_A + cur*(2*SZ_AB) + SZ_AB);
            const _Float16* Bh = (const _Float16*)(smem + OFF_B + cur*(2*SZ_AB));
            const _Float16* Bl = (const _Float16*)(smem + OFF_B + cur*(2*SZ_AB) + SZ_AB);
            half8 ah[2], al[2], bh[4], bl[4];
            #pragma unroll
            for (int tf = 0; tf < 2; ++tf) {
                ah[tf] = *(const half8*)(Ah + aoff[tf]);
                al[tf] = *(const half8*)(Al + aoff[tf]);
            }
            #pragma unroll
            for (int jf = 0; jf < 4; ++jf) {
                bh[jf] = *(const half8*)(Bh + boff[jf]);
                bl[jf] = *(const half8*)(Bl + boff[jf]);
            }
            #pragma unroll
            for (int tf = 0; tf < 2; ++tf)
                #pragma unroll
                for (int jf = 0; jf < 4; ++jf) {
                    acc1[tf][jf] = mfma16(ah[tf], bh[jf], acc1[tf][jf]);
                    acc1[tf][jf] = mfma16(ah[tf], bl[jf], acc1[tf][jf]);
                    acc1[tf][jf] = mfma16(al[tf], bh[jf], acc1[tf][jf]);
                }
            if (more) {                      // write NEXT buffer (no race with cur reads)
                _Float16* nAh = (_Float16*)(smem + OFF_A + (cur^1)*(2*SZ_AB));
                _Float16* nAl = (_Float16*)(smem + OFF_A + (cur^1)*(2*SZ_AB) + SZ_AB);
                _Float16* nBh = (_Float16*)(smem + OFF_B + (cur^1)*(2*SZ_AB));
                _Float16* nBl = (_Float16*)(smem + OFF_B + (cur^1)*(2*SZ_AB) + SZ_AB);
                half8 hh, hl;
                split8(ra0, ra1, hh, hl);
                *(half8*)(nAh + soff) = hh; *(half8*)(nAl + soff) = hl;
                *(half8*)(nBh + soff) = rbh; *(half8*)(nBl + soff) = rbl;
            }
            cur ^= 1;
            __syncthreads();                 // ONE barrier per k-step
        }

        // GELU + split -> wave-private H tile (no barrier: same-wave LDS ordering)
        #pragma unroll
        for (int tf = 0; tf < 2; ++tf)
            #pragma unroll
            for (int jf = 0; jf < 4; ++jf)
                #pragma unroll
                for (int r = 0; r < 4; ++r) {
                    const float v = acc1[tf][jf][r];
                    const float g = 0.5f * v * (1.0f + erff(v * 0.70710678118654752f));
                    const _Float16 gh = (_Float16)g;
                    const _Float16 gl = (_Float16)(g - (float)gh);
                    const int o = (tg*32 + tf*16 + lg*4 + r) * HLD + jg*64 + jf*16 + l15;
                    Hh[o] = gh; Hl[o] = gl;
                }

        // GEMM2 over this wave's j-half; W2 fp16 planes straight from global (L2)
        #pragma unroll
        for (int ks2 = 0; ks2 < 2; ++ks2) {
            const int j2 = jg*64 + ks2*32 + lg*8;
            half8 a2h[2], a2l[2];
            #pragma unroll
            for (int tf = 0; tf < 2; ++tf) {
                const int o = (tg*32 + tf*16 + l15) * HLD + j2;
                a2h[tf] = *(const half8*)(Hh + o);
                a2l[tf] = *(const half8*)(Hl + o);
            }
            const size_t wcol = (size_t)(jc*BJ) + j2;
            #pragma unroll
            for (int ef = 0; ef < 4; ++ef) {
                const size_t wo = (size_t)(ef*16 + l15) * JD + wcol;
                half8 b2h = *(const half8*)(W2h + wo);
                half8 b2l = *(const half8*)(W2l + wo);
                #pragma unroll
                for (int tf = 0; tf < 2; ++tf) {
                    lacc[tf][ef] = mfma16(a2h[tf], b2h, lacc[tf][ef]);
                    lacc[tf][ef] = mfma16(a2h[tf], b2l, lacc[tf][ef]);
                    lacc[tf][ef] = mfma16(a2l[tf], b2h, lacc[tf][ef]);
                }
            }
        }
    }

    // ---- epilogue: reduce jg halves into Lred, softmax + top-2, write outputs
    __syncthreads();   // all GEMM2 H-reads done before Lred aliases H
    float* const Lred = (float*)(smem + OFF_LRED);
    if (jg == 1) {
        #pragma unroll
        for (int tf = 0; tf < 2; ++tf)
            #pragma unroll
            for (int ef = 0; ef < 4; ++ef)
                #pragma unroll
                for (int r = 0; r < 4; ++r)
                    Lred[(tg*32 + tf*16 + lg*4 + r) * 68 + ef*16 + l15] = lacc[tf][ef][r];
    }
    __syncthreads();
    if (jg == 0) {
        #pragma unroll
        for (int tf = 0; tf < 2; ++tf)
            #pragma unroll
            for (int ef = 0; ef < 4; ++ef)
                #pragma unroll
                for (int r = 0; r < 4; ++r) {
                    const int o = (tg*32 + tf*16 + lg*4 + r) * 68 + ef*16 + l15;
                    Lred[o] += lacc[tf][ef][r];
                }
    }
    __syncthreads();

    float* const mA   = (float*)(smem + OFF_EPI);
    float* const invA = mA + BM;
    int*   const i1A  = (int*)(invA + BM);
    int*   const i2A  = i1A + BM;
    float* const rp1A = (float*)(i2A + BM);
    float* const rp2A = rp1A + BM;

    if (tid < BM) {
        const float* row = Lred + tid * 68;
        float m = -3.402823466e38f;
        for (int e = 0; e < NE; ++e) m = fmaxf(m, row[e]);
        float s = 0.f, v1 = -3.402823466e38f, v2 = -3.402823466e38f;
        int i1 = 0, i2 = 0;
        for (int e = 0; e < NE; ++e) {
            const float v = row[e];
            s += expf(v - m);
            if (v > v1)      { v2 = v1; i2 = i1; v1 = v; i1 = e; }
            else if (v > v2) { v2 = v; i2 = e; }
        }
        const float inv = 1.f / s;
        const float p1 = fminf(expf(v1 - m) * inv + EPSV, 1.f - EPSV);
        const float p2 = fminf(expf(v2 - m) * inv + EPSV, 1.f - EPSV);
        mA[tid] = m; invA[tid] = inv; i1A[tid] = i1; i2A[tid] = i2;
        const float den = p1 + p2;
        rp1A[tid] = p1 / den; rp2A[tid] = p2 / den;
    }
    __syncthreads();

    for (int idx = tid; idx < BM * NE; idx += NTH) {
        const int r = idx >> 6, e = idx & 63;
        const size_t o = (size_t)(t0 + r) * NE + e;
        const float p = fminf(expf(Lred[r * 68 + e] - mA[r]) * invA[r] + EPSV, 1.f - EPSV);
        const int b1 = (e == i1A[r]), b2 = (e == i2A[r]);
        out_probs[o] = p;
        out_mask[o]  = (b1 | b2) ? 1.f : 0.f;
        out_rp[o]    = b1 ? rp1A[r] : (b2 ? rp2A[r] : 0.f);
    }
    if (tid < BM * 2) {
        const int r = tid >> 1, q = tid & 1;
        out_topi[(size_t)(t0 + r) * 2 + q] = (float)(q ? i2A[r] : i1A[r]);
    }
}

// ======== fallback: proven round-2 kernel (used if ws too small) ========
#define FBM    128
#define FBJ    128
#define FHLD   136
#define FOFF_A1H 0
#define FOFF_A1L (FOFF_A1H + FBM*KC*2)
#define FOFF_B1H (FOFF_A1L + FBM*KC*2)
#define FOFF_B1L (FOFF_B1H + FBJ*KC*2)
#define FOFF_HH  (FOFF_B1L + FBJ*KC*2)
#define FOFF_HL  (FOFF_HH  + FBM*FHLD*2)
#define FOFF_W2H (FOFF_HL  + FBM*FHLD*2)
#define FOFF_W2L (FOFF_W2H + NE*FHLD*2)
#define FLDS_TOTAL (FOFF_W2L + NE*FHLD*2)
#define FOFF_LRED FOFF_HH
#define FOFF_EPI  (FOFF_LRED + FBM*68*4)

__global__ __launch_bounds__(NTH, 2)
void router_fb(const float* __restrict__ inp, const float* __restrict__ cnd,
               const float* __restrict__ W1, const float* __restrict__ W2,
               float* __restrict__ out_mask, float* __restrict__ out_topi,
               float* __restrict__ out_rp, float* __restrict__ out_probs)
{
    __shared__ __align__(16) char smem[FLDS_TOTAL];
    _Float16* const A1h = (_Float16*)(smem + FOFF_A1H);
    _Float16* const A1l = (_Float16*)(smem + FOFF_A1L);
    _Float16* const B1h = (_Float16*)(smem + FOFF_B1H);
    _Float16* const B1l = (_Float16*)(smem + FOFF_B1L);
    _Float16* const Hh  = (_Float16*)(smem + FOFF_HH);
    _Float16* const Hl  = (_Float16*)(smem + FOFF_HL);
    _Float16* const W2h = (_Float16*)(smem + FOFF_W2H);
    _Float16* const W2l = (_Float16*)(smem + FOFF_W2L);

    const int tid  = threadIdx.x;
    const int lane = tid & 63;
    const int w    = tid >> 6;
    const int tg   = w >> 1;
    const int jg   = w & 1;
    const int l15  = lane & 15;
    const int lg   = lane >> 4;
    const int lk8  = lg * 8;
    const int t0   = blockIdx.x * FBM;
    const int srow = tid >> 2;
    const int sk8  = (tid & 3) * 8;
    const int soff = srow * KC + sk8;
    const int we   = tid >> 3;
    const int wj16 = (tid & 7) * 16;

    const f32x4 vzero = {0.f, 0.f, 0.f, 0.f};
    f32x4 lacc[2][4];
    #pragma unroll
    for (int tf = 0; tf < 2; ++tf)
        #pragma unroll
        for (int ef = 0; ef < 4; ++ef) lacc[tf][ef] = vzero;

    int aoff[2], boff[4], a2base[2], b2base[4];
    #pragma unroll
    for (int tf = 0; tf < 2; ++tf) {
        aoff[tf]   = (tg*32 + tf*16 + l15) * KC + lk8;
        a2base[tf] = (tg*32 + tf*16 + l15) * FHLD;
    }
    #pragma unroll
    for (int jf = 0; jf < 4; ++jf) boff[jf] = (jg*64 + jf*16 + l15) * KC + lk8;
    #pragma unroll
    for (int ef = 0; ef < 4; ++ef) b2base[ef] = (ef*16 + l15) * FHLD;

    const float* const xrowA = inp + (size_t)(t0 + srow) * D0;
    const float* const xrowC = cnd + (size_t)(t0 + srow) * DCC;

    for (int jc = 0; jc < JD/FBJ; ++jc) {
        const int bj0 = jc * FBJ;
        const float* const w1row = W1 + (size_t)(bj0 + srow) * DIN;
        float4 ra0 = *(const float4*)(xrowA + sk8);
        float4 ra1 = *(const float4*)(xrowA + sk8 + 4);
        float4 rb0 = *(const float4*)(w1row + sk8);
        float4 rb1 = *(const float4*)(w1row + sk8 + 4);
        {
            half8 hh, hl;
            split8(ra0, ra1, hh, hl);
            *(half8*)(A1h + soff) = hh; *(half8*)(A1l + soff) = hl;
            split8(rb0, rb1, hh, hl);
            *(half8*)(B1h + soff) = hh; *(half8*)(B1l + soff) = hl;
        }
        f32x4 acc1[2][4];
        #pragma unroll
        for (int tf = 0; tf < 2; ++tf)
            #pragma unroll
            for (int jf = 0; jf < 4; ++jf) acc1[tf][jf] = vzero;
        __syncthreads();

        for (int ks = 0; ks < NKS; ++ks) {
            if (ks + 1 < NKS) {
                const int k = (ks + 1) * KC + sk8;
                const float* srcA = (k < D0) ? (xrowA + k) : (xrowC + (k - D0));
                ra0 = *(const float4*)srcA;
                ra1 = *(const float4*)(srcA + 4);
                rb0 = *(const float4*)(w1row + k);
                rb1 = *(const float4*)(w1row + k + 4);
            }
            half8 ah[2], al[2], bh[4], bl[4];
            #pragma unroll
            for (int tf = 0; tf < 2; ++tf) {
                ah[tf] = *(const half8*)(A1h + aoff[tf]);
                al[tf] = *(const half8*)(A1l + aoff[tf]);
            }
            #pragma unroll
            for (int jf = 0; jf < 4; ++jf) {
                bh[jf] = *(const half8*)(B1h + boff[jf]);
                bl[jf] = *(const half8*)(B1l + boff[jf]);
            }
            #pragma unroll
            for (int tf = 0; tf < 2; ++tf)
                #pragma unroll
                for (int jf = 0; jf < 4; ++jf) {
                    acc1[tf][jf] = mfma16(ah[tf], bh[jf], acc1[tf][jf]);
                    acc1[tf][jf] = mfma16(ah[tf], bl[jf], acc1[tf][jf]);
                    acc1[tf][jf] = mfma16(al[tf], bh[jf], acc1[tf][jf]);
                }
            __syncthreads();
            if (ks + 1 < NKS) {
                half8 hh, hl;
                split8(ra0, ra1, hh, hl);
                *(half8*)(A1h + soff) = hh; *(half8*)(A1l + soff) = hl;
                split8(rb0, rb1, hh, hl);
                *(half8*)(B1h + soff) = hh; *(half8*)(B1l + soff) = hl;
                __syncthreads();
            }
        }
        #pragma unroll
        for (int tf = 0; tf < 2; ++tf)
            #pragma unroll
            for (int jf = 0; jf < 4; ++jf)
                #pragma unroll
                for (int r = 0; r < 4; ++r) {
                    float v = acc1[tf][jf][r];
                    float g = 0.5f * v * (1.0f + erff(v * 0.70710678118654752f));
                    _Float16 ghi = (_Float16)g;
                    _Float16 glo = (_Float16)(g - (float)ghi);
                    const int o = (tg*32 + tf*16 + lg*4 + r) * FHLD + (jg*64 + jf*16 + l15);
                    Hh[o] = ghi; Hl[o] = glo;
                }
        {
            const float* src = W2 + (size_t)we * JD + bj0 + wj16;
            float4 q0 = *(const float4*)src;
            float4 q1 = *(const float4*)(src + 4);
            float4 q2 = *(const float4*)(src + 8);
            float4 q3 = *(const float4*)(src + 12);
            half8 hh, hl;
            const int o = we * FHLD + wj16;
            split8(q0, q1, hh, hl);
            *(half8*)(W2h + o) = hh;     *(half8*)(W2l + o) = hl;
            split8(q2, q3, hh, hl);
            *(half8*)(W2h + o + 8) = hh; *(half8*)(W2l + o + 8) = hl;
        }
        __syncthreads();
        #pragma unroll
        for (int ks2 = 0; ks2 < 2; ++ks2) {
            const int j2 = jg*64 + ks2*32 + lk8;
            half8 a2h[2], a2l[2];
            #pragma unroll
            for (int tf = 0; tf < 2; ++tf) {
                a2h[tf] = *(const half8*)(Hh + a2base[tf] + j2);
                a2l[tf] = *(const half8*)(Hl + a2base[tf] + j2);
            }
            #pragma unroll
            for (int ef = 0; ef < 4; ++ef) {
                half8 b2h = *(const half8*)(W2h + b2base[ef] + j2);
                half8 b2l = *(const half8*)(W2l + b2base[ef] + j2);
                #pragma unroll
                for (int tf = 0; tf < 2; ++tf) {
                    lacc[tf][ef] = mfma16(a2h[tf], b2h, lacc[tf][ef]);
                    lacc[tf][ef] = mfma16(a2h[tf], b2l, lacc[tf][ef]);
                    lacc[tf][ef] = mfma16(a2l[tf], b2h, lacc[tf][ef]);
                }
            }
        }
        __syncthreads();
    }

    float* const Lred = (float*)(smem + FOFF_LRED);
    if (jg == 1) {
        #pragma unroll
        for (int tf = 0; tf < 2; ++tf)
            #pragma unroll
            for (int ef = 0; ef < 4; ++ef)
                #pragma unroll
                for (int r = 0; r < 4; ++r)
                    Lred[(tg*32 + tf*16 + lg*4 + r) * 68 + ef*16 + l15] = lacc[tf][ef][r];
    }
    __syncthreads();
    if (jg == 0) {
        #pragma unroll
        for (int tf = 0; tf < 2; ++tf)
            #pragma unroll
            for (int ef = 0; ef < 4; ++ef)
                #pragma unroll
                for (int r = 0; r < 4; ++r) {
                    const int o = (tg*32 + tf*16 + lg*4 + r) * 68 + ef*16 + l15;
                    Lred[o] += lacc[tf][ef][r];
                }
    }
    __syncthreads();

    float* const mA   = (float*)(smem + FOFF_EPI);
    float* const invA = mA + FBM;
    int*   const i1A  = (int*)(invA + FBM);
    int*   const i2A  = i1A + FBM;
    float* const rp1A = (float*)(i2A + FBM);
    float* const rp2A = rp1A + FBM;

    if (tid < FBM) {
        const float* row = Lred + tid * 68;
        float m = -3.402823466e38f;
        for (int e = 0; e < NE; ++e) m = fmaxf(m, row[e]);
        float s = 0.f, v1 = -3.402823466e38f, v2 = -3.402823466e38f;
        int i1 = 0, i2 = 0;
        for (int e = 0; e < NE; ++e) {
            const float v = row[e];
            s += expf(v - m);
            if (v > v1)      { v2 = v1; i2 = i1; v1 = v; i1 = e; }
            else if (v > v2) { v2 = v; i2 = e; }
        }
        const float inv = 1.f / s;
        const float p1 = fminf(expf(v1 - m) * inv + EPSV, 1.f - EPSV);
        const float p2 = fminf(expf(v2 - m) * inv + EPSV, 1.f - EPSV);
        mA[tid] = m; invA[tid] = inv; i1A[tid] = i1; i2A[tid] = i2;
        const float den = p1 + p2;
        rp1A[tid] = p1 / den; rp2A[tid] = p2 / den;
    }
    __syncthreads();

    for (int idx = tid; idx < FBM * NE; idx += NTH) {
        const int r = idx >> 6, e = idx & 63;
        const size_t o = (size_t)(t0 + r) * NE + e;
        const float p = fminf(expf(Lred[r * 68 + e] - mA[r]) * invA[r] + EPSV, 1.f - EPSV);
        const int b1 = (e == i1A[r]), b2 = (e == i2A[r]);
        out_probs[o] = p;
        out_mask[o]  = (b1 | b2) ? 1.f : 0.f;
        out_rp[o]    = b1 ? rp1A[r] : (b2 ? rp2A[r] : 0.f);
    }
    if (tid < FBM * 2) {
        const int r = tid >> 1, q = tid & 1;
        out_topi[(size_t)(t0 + r) * 2 + q] = (float)(q ? i2A[r] : i1A[r]);
    }
}

extern "C" void kernel_launch(void* const* d_in, const int* in_sizes, int n_in,
                              void* d_out, int out_size, void* d_ws, size_t ws_size,
                              hipStream_t stream) {
    const float* inp = (const float*)d_in[0];
    const float* cnd = (const float*)d_in[1];
    const float* W1  = (const float*)d_in[2];
    const float* W2  = (const float*)d_in[3];

    float* out = (float*)d_out;
    const size_t NT = (size_t)N_TOK;
    float* out_mask  = out;
    float* out_topi  = out + NT * NE;
    float* out_rp    = out + NT * NE + NT * 2;
    float* out_probs = out + NT * NE + NT * 2 + NT * NE;

    if (ws_size >= WS_REQ) {
        _Float16* W1h = (_Float16*)d_ws;
        _Float16* W1l = W1h + W1_N;
        _Float16* W2h = W1l + W1_N;
        _Float16* W2l = W2h + W2_N;
        hipLaunchKernelGGL(presplit, dim3(1024), dim3(256), 0, stream, W1, W1h, W1l, W1_N/4);
        hipLaunchKernelGGL(presplit, dim3(192),  dim3(256), 0, stream, W2, W2h, W2l, W2_N/4);
        hipLaunchKernelGGL(router_v5, dim3(N_TOK / BM), dim3(NTH), 0, stream,
                           inp, cnd, W1h, W1l, W2h, W2l,
                           out_mask, out_topi, out_rp, out_probs);
    } else {
        hipLaunchKernelGGL(router_fb, dim3(N_TOK / FBM), dim3(NTH), 0, stream,
                           inp, cnd, W1, W2, out_mask, out_topi, out_rp, out_probs);
    }
}

// Round 6
// 1389.067 us; speedup vs baseline: 3.8279x; 1.0135x over previous
//
#include <hip/hip_runtime.h>
#include <cmath>

// RouterCond fused, round 6: r5 math (fp16x2-split MFMA, pre-split W1/W2 planes,
// W2-from-global GEMM2) restructured to 76 KB LDS -> 2 blocks/CU, two barrier
// domains cross-cover stalls. Single-buffer 2-barrier k-loop (r2-proven).
#define N_TOK 32768
#define D0    1024
#define DCC   512
#define DIN   1536
#define JD    3072
#define NE    64
#define BM    128
#define BJ    128
#define KC    32
#define NJC   (JD/BJ)      // 24
#define NKS   (DIN/KC)     // 48
#define NTH   512
#define ALD   40           // A/B tile row stride in halves (20 dw: full bank coverage)
#define HS    36           // H slab row stride in halves (18 dw: full coverage)
#define EPSV  1e-9f

typedef _Float16 half8 __attribute__((ext_vector_type(8)));
typedef float    f32x4 __attribute__((ext_vector_type(4)));

// ---- LDS layout (bytes); total 77824 -> 2 blocks/CU (<= 80 KiB each)
#define OFF_AH 0                       // [128][40] halves = 10240
#define OFF_AL 10240
#define OFF_BH 20480
#define OFF_BL 30720
#define OFF_H  40960                   // 8 wave slabs x (Hh 2304 + Hl 2304)
#define LDS_TOTAL (OFF_H + 8*4608)     // 77824
#define OFF_LRED OFF_H                 // [128][68] f32 = 34816 <= 36864 (H dead)
#define OFF_EPI  OFF_AH                // 3072 <= 10240 (A dead)

// ---- workspace: pre-split fp16 hi/lo planes of W1, W2
#define W1_N (JD*DIN)
#define W2_N (NE*JD)
#define WS_REQ ((size_t)(W1_N + W2_N) * 4)   // 19,660,800 B

__device__ __forceinline__ f32x4 mfma16(half8 a, half8 b, f32x4 c) {
    return __builtin_amdgcn_mfma_f32_16x16x32_f16(a, b, c, 0, 0, 0);
}

__device__ __forceinline__ void split8(const float4 v0, const float4 v1, half8& hh, half8& hl) {
    float f[8] = {v0.x, v0.y, v0.z, v0.w, v1.x, v1.y, v1.z, v1.w};
    #pragma unroll
    for (int i = 0; i < 8; ++i) {
        _Float16 h = (_Float16)f[i];
        hh[i] = h;
        hl[i] = (_Float16)(f[i] - (float)h);
    }
}

// -------- prologue: split fp32 weights into fp16 hi/lo planes --------
__global__ void presplit(const float* __restrict__ src, _Float16* __restrict__ hi,
                         _Float16* __restrict__ lo, int n4) {
    typedef _Float16 half4v __attribute__((ext_vector_type(4)));
    int i = blockIdx.x * blockDim.x + threadIdx.x;
    const int stride = gridDim.x * blockDim.x;
    for (; i < n4; i += stride) {
        float4 v = *(const float4*)(src + (size_t)i * 4);
        half4v h, l;
        float f[4] = {v.x, v.y, v.z, v.w};
        #pragma unroll
        for (int q = 0; q < 4; ++q) {
            _Float16 hh = (_Float16)f[q];
            h[q] = hh;
            l[q] = (_Float16)(f[q] - (float)hh);
        }
        *(half4v*)(hi + (size_t)i * 4) = h;
        *(half4v*)(lo + (size_t)i * 4) = l;
    }
}

// -------- main fused kernel --------
__global__ __launch_bounds__(NTH, 2)
void router_v6(const float* __restrict__ inp, const float* __restrict__ cnd,
               const _Float16* __restrict__ W1h, const _Float16* __restrict__ W1l,
               const _Float16* __restrict__ W2h, const _Float16* __restrict__ W2l,
               float* __restrict__ out_mask, float* __restrict__ out_topi,
               float* __restrict__ out_rp, float* __restrict__ out_probs)
{
    __shared__ __align__(16) char smem[LDS_TOTAL];
    _Float16* const Ah = (_Float16*)(smem + OFF_AH);
    _Float16* const Al = (_Float16*)(smem + OFF_AL);
    _Float16* const Bh = (_Float16*)(smem + OFF_BH);
    _Float16* const Bl = (_Float16*)(smem + OFF_BL);

    const int tid  = threadIdx.x;
    const int lane = tid & 63;
    const int w    = tid >> 6;      // wave 0..7
    const int tg   = w >> 1;        // token group: rows tg*32..+31 (4 groups)
    const int jg   = w & 1;         // j half: cols jg*64..+63
    const int l15  = lane & 15;
    const int lg   = lane >> 4;     // 0..3
    const int t0   = blockIdx.x * BM;

    // wave-private H slab: [32][HS] halves, hi then lo
    _Float16* const sHh = (_Float16*)(smem + OFF_H + w * 4608);
    _Float16* const sHl = sHh + 1152;

    // staging: 512 threads cover 128 rows x 32 k (8 halves each)
    const int srow = tid >> 2;
    const int sk8  = (tid & 3) * 8;
    const int soff = srow * ALD + sk8;

    int aoff[2], boff[4];
    #pragma unroll
    for (int tf = 0; tf < 2; ++tf) aoff[tf] = (tg*32 + tf*16 + l15) * ALD + lg*8;
    #pragma unroll
    for (int jf = 0; jf < 4; ++jf) boff[jf] = (jg*64 + jf*16 + l15) * ALD + lg*8;

    const f32x4 vzero = {0.f, 0.f, 0.f, 0.f};
    f32x4 lacc[2][4];                    // [tf][ef] logits, partial over jg
    #pragma unroll
    for (int tf = 0; tf < 2; ++tf)
        #pragma unroll
        for (int ef = 0; ef < 4; ++ef) lacc[tf][ef] = vzero;

    const float* const xA = inp + (size_t)(t0 + srow) * D0;
    const float* const xC = cnd + (size_t)(t0 + srow) * DCC;

    for (int jc = 0; jc < NJC; ++jc) {
        const _Float16* const w1hr = W1h + (size_t)(jc*BJ + srow) * DIN;
        const _Float16* const w1lr = W1l + (size_t)(jc*BJ + srow) * DIN;

        f32x4 acc1[2][4];
        #pragma unroll
        for (int tf = 0; tf < 2; ++tf)
            #pragma unroll
            for (int jf = 0; jf < 4; ++jf) acc1[tf][jf] = vzero;

        // prologue: stage k-step 0 (k<1024 -> inp side)
        {
            float4 ra0 = *(const float4*)(xA + sk8);
            float4 ra1 = *(const float4*)(xA + sk8 + 4);
            half8 rbh = *(const half8*)(w1hr + sk8);
            half8 rbl = *(const half8*)(w1lr + sk8);
            half8 hh, hl;
            split8(ra0, ra1, hh, hl);
            *(half8*)(Ah + soff) = hh; *(half8*)(Al + soff) = hl;
            *(half8*)(Bh + soff) = rbh; *(half8*)(Bl + soff) = rbl;
        }
        __syncthreads();

        for (int ks = 0; ks < NKS; ++ks) {
            const bool more = (ks + 1 < NKS);
            float4 ra0, ra1; half8 rbh, rbl;
            if (more) {                      // prefetch next k-step into regs
                const int k = (ks + 1) * KC + sk8;
                const float* sA = (k < D0) ? (xA + k) : (xC + k - D0);
                ra0 = *(const float4*)sA;
                ra1 = *(const float4*)(sA + 4);
                rbh = *(const half8*)(w1hr + k);
                rbl = *(const half8*)(w1lr + k);
            }
            half8 ah[2], al[2], bh[4], bl[4];
            #pragma unroll
            for (int tf = 0; tf < 2; ++tf) {
                ah[tf] = *(const half8*)(Ah + aoff[tf]);
                al[tf] = *(const half8*)(Al + aoff[tf]);
            }
            #pragma unroll
            for (int jf = 0; jf < 4; ++jf) {
                bh[jf] = *(const half8*)(Bh + boff[jf]);
                bl[jf] = *(const half8*)(Bl + boff[jf]);
            }
            #pragma unroll
            for (int tf = 0; tf < 2; ++tf)
                #pragma unroll
                for (int jf = 0; jf < 4; ++jf) {
                    acc1[tf][jf] = mfma16(ah[tf], bh[jf], acc1[tf][jf]);
                    acc1[tf][jf] = mfma16(ah[tf], bl[jf], acc1[tf][jf]);
                    acc1[tf][jf] = mfma16(al[tf], bh[jf], acc1[tf][jf]);
                }
            __syncthreads();                 // frag reads done
            if (more) {
                half8 hh, hl;
                split8(ra0, ra1, hh, hl);
                *(half8*)(Ah + soff) = hh; *(half8*)(Al + soff) = hl;
                *(half8*)(Bh + soff) = rbh; *(half8*)(Bl + soff) = rbl;
                __syncthreads();             // writes visible
            }
        }

        // ---- GEMM2: two 32-col half-passes through the wave-private H slab.
        // Same-wave ds_write->ds_read ordering handled by compiler lgkmcnt.
        #pragma unroll
        for (int h2 = 0; h2 < 2; ++h2) {
            #pragma unroll
            for (int c = 0; c < 2; ++c) {
                const int jf = h2*2 + c;
                #pragma unroll
                for (int tf = 0; tf < 2; ++tf)
                    #pragma unroll
                    for (int r = 0; r < 4; ++r) {
                        const float v = acc1[tf][jf][r];
                        const float g = 0.5f * v * (1.0f + erff(v * 0.70710678118654752f));
                        const _Float16 gh = (_Float16)g;
                        const _Float16 gl = (_Float16)(g - (float)gh);
                        const int o = (tf*16 + lg*4 + r) * HS + c*16 + l15;
                        sHh[o] = gh; sHl[o] = gl;
                    }
            }
            const int jbase = jc*BJ + jg*64 + h2*32 + lg*8;
            half8 a2h[2], a2l[2];
            #pragma unroll
            for (int tf = 0; tf < 2; ++tf) {
                const int o = (tf*16 + l15) * HS + lg*8;
                a2h[tf] = *(const half8*)(sHh + o);
                a2l[tf] = *(const half8*)(sHl + o);
            }
            #pragma unroll
            for (int ef = 0; ef < 4; ++ef) {
                const size_t wo = (size_t)(ef*16 + l15) * JD + jbase;
                half8 b2h = *(const half8*)(W2h + wo);
                half8 b2l = *(const half8*)(W2l + wo);
                #pragma unroll
                for (int tf = 0; tf < 2; ++tf) {
                    lacc[tf][ef] = mfma16(a2h[tf], b2h, lacc[tf][ef]);
                    lacc[tf][ef] = mfma16(a2h[tf], b2l, lacc[tf][ef]);
                    lacc[tf][ef] = mfma16(a2l[tf], b2h, lacc[tf][ef]);
                }
            }
        }
    }

    // ---- epilogue: reduce jg halves into Lred, softmax + top-2, write outputs
    __syncthreads();   // all GEMM2 H-reads done before Lred aliases H
    float* const Lred = (float*)(smem + OFF_LRED);
    if (jg == 1) {
        #pragma unroll
        for (int tf = 0; tf < 2; ++tf)
            #pragma unroll
            for (int ef = 0; ef < 4; ++ef)
                #pragma unroll
                for (int r = 0; r < 4; ++r)
                    Lred[(tg*32 + tf*16 + lg*4 + r) * 68 + ef*16 + l15] = lacc[tf][ef][r];
    }
    __syncthreads();
    if (jg == 0) {
        #pragma unroll
        for (int tf = 0; tf < 2; ++tf)
            #pragma unroll
            for (int ef = 0; ef < 4; ++ef)
                #pragma unroll
                for (int r = 0; r < 4; ++r) {
                    const int o = (tg*32 + tf*16 + lg*4 + r) * 68 + ef*16 + l15;
                    Lred[o] += lacc[tf][ef][r];
                }
    }
    __syncthreads();

    float* const mA   = (float*)(smem + OFF_EPI);
    float* const invA = mA + BM;
    int*   const i1A  = (int*)(invA + BM);
    int*   const i2A  = i1A + BM;
    float* const rp1A = (float*)(i2A + BM);
    float* const rp2A = rp1A + BM;

    if (tid < BM) {
        const float* row = Lred + tid * 68;
        float m = -3.402823466e38f;
        for (int e = 0; e < NE; ++e) m = fmaxf(m, row[e]);
        float s = 0.f, v1 = -3.402823466e38f, v2 = -3.402823466e38f;
        int i1 = 0, i2 = 0;
        for (int e = 0; e < NE; ++e) {
            const float v = row[e];
            s += expf(v - m);
            if (v > v1)      { v2 = v1; i2 = i1; v1 = v; i1 = e; }
            else if (v > v2) { v2 = v; i2 = e; }
        }
        const float inv = 1.f / s;
        const float p1 = fminf(expf(v1 - m) * inv + EPSV, 1.f - EPSV);
        const float p2 = fminf(expf(v2 - m) * inv + EPSV, 1.f - EPSV);
        mA[tid] = m; invA[tid] = inv; i1A[tid] = i1; i2A[tid] = i2;
        const float den = p1 + p2;
        rp1A[tid] = p1 / den; rp2A[tid] = p2 / den;
    }
    __syncthreads();

    for (int idx = tid; idx < BM * NE; idx += NTH) {
        const int r = idx >> 6, e = idx & 63;
        const size_t o = (size_t)(t0 + r) * NE + e;
        const float p = fminf(expf(Lred[r * 68 + e] - mA[r]) * invA[r] + EPSV, 1.f - EPSV);
        const int b1 = (e == i1A[r]), b2 = (e == i2A[r]);
        out_probs[o] = p;
        out_mask[o]  = (b1 | b2) ? 1.f : 0.f;
        out_rp[o]    = b1 ? rp1A[r] : (b2 ? rp2A[r] : 0.f);
    }
    if (tid < BM * 2) {
        const int r = tid >> 1, q = tid & 1;
        out_topi[(size_t)(t0 + r) * 2 + q] = (float)(q ? i2A[r] : i1A[r]);
    }
}

extern "C" void kernel_launch(void* const* d_in, const int* in_sizes, int n_in,
                              void* d_out, int out_size, void* d_ws, size_t ws_size,
                              hipStream_t stream) {
    const float* inp = (const float*)d_in[0];
    const float* cnd = (const float*)d_in[1];
    const float* W1  = (const float*)d_in[2];
    const float* W2  = (const float*)d_in[3];

    float* out = (float*)d_out;
    const size_t NT = (size_t)N_TOK;
    float* out_mask  = out;
    float* out_topi  = out + NT * NE;
    float* out_rp    = out + NT * NE + NT * 2;
    float* out_probs = out + NT * NE + NT * 2 + NT * NE;

    _Float16* W1h = (_Float16*)d_ws;
    _Float16* W1l = W1h + W1_N;
    _Float16* W2h = W1l + W1_N;
    _Float16* W2l = W2h + W2_N;
    hipLaunchKernelGGL(presplit, dim3(1024), dim3(256), 0, stream, W1, W1h, W1l, W1_N/4);
    hipLaunchKernelGGL(presplit, dim3(192),  dim3(256), 0, stream, W2, W2h, W2l, W2_N/4);
    hipLaunchKernelGGL(router_v6, dim3(N_TOK / BM), dim3(NTH), 0, stream,
                       inp, cnd, W1h, W1l, W2h, W2l,
                       out_mask, out_topi, out_rp, out_probs);
}

// Round 7
// 1280.974 us; speedup vs baseline: 4.1509x; 1.0844x over previous
//
#include <hip/hip_runtime.h>
#include <cmath>

// RouterCond fused, round 7: K-oct-major granule LDS layout (conflict-free
// b128 frag reads), global_load_lds direct staging of pre-transposed fp16
// hi/lo W1 planes, single-barrier dbuf k-loop, issue-early/write-late x path.
#define N_TOK 32768
#define D0    1024
#define DCC   512
#define DIN   1536
#define JD    3072
#define NE    64
#define BM    128
#define BJ    128
#define KC    32
#define NJC   (JD/BJ)      // 24
#define NKS   (DIN/KC)     // 48
#define NTH   512
#define HS    36           // H slab row stride in halves (conflict-free, r6-proven)
#define EPSV  1e-9f

typedef _Float16 half8 __attribute__((ext_vector_type(8)));
typedef float    f32x4 __attribute__((ext_vector_type(4)));

// ---- LDS layout: granules of 16 B. Tile = [plane(2)][koct(4)][row(128)] granules.
#define SZ_BUF 16384                  // one A or B buffer (2 planes)
#define OFF_A  0                      // A buffers: 0, 16384
#define OFF_B  32768                  // B buffers: 32768, 49152
#define OFF_H  65536                  // 8 wave slabs x 4608 B
#define LDS_TOTAL (OFF_H + 8*4608)    // 102400
#define OFF_LRED OFF_H                // [128][68] f32 = 34816 <= 36864 (H dead)
#define OFF_EPI  OFF_A                // epilogue scalars alias dead A

// ---- workspace: pre-split + pre-transposed fp16 planes
// W1t[ko][j] granule (8 halves) = W1[j][ko*8..+8); ko in [0,192), j in [0,3072)
// W2t[jo][e] granule            = W2[e][jo*8..+8); jo in [0,384),  e in [0,64)
#define W1T_G (192*3072)              // 589824 granules
#define W2T_G (384*64)                // 24576 granules

__device__ __forceinline__ f32x4 mfma16(half8 a, half8 b, f32x4 c) {
    return __builtin_amdgcn_mfma_f32_16x16x32_f16(a, b, c, 0, 0, 0);
}

__device__ __forceinline__ void split8(const float4 v0, const float4 v1, half8& hh, half8& hl) {
    float f[8] = {v0.x, v0.y, v0.z, v0.w, v1.x, v1.y, v1.z, v1.w};
    #pragma unroll
    for (int i = 0; i < 8; ++i) {
        _Float16 h = (_Float16)f[i];
        hh[i] = h;
        hl[i] = (_Float16)(f[i] - (float)h);
    }
}

__device__ __forceinline__ void gload16(const void* g, void* l) {
    __builtin_amdgcn_global_load_lds(
        (const __attribute__((address_space(1))) unsigned int*)g,
        (__attribute__((address_space(3))) unsigned int*)l, 16, 0, 0);
}

// -------- prologue kernels: split + transpose weights into granule layout ----
__global__ void presplit_w1t(const float* __restrict__ W1,
                             _Float16* __restrict__ hi, _Float16* __restrict__ lo) {
    int g = blockIdx.x * blockDim.x + threadIdx.x;   // granule id
    if (g >= W1T_G) return;
    const int j  = g % JD;
    const int ko = g / JD;
    const float* src = W1 + (size_t)j * DIN + ko * 8;
    float4 v0 = *(const float4*)src;
    float4 v1 = *(const float4*)(src + 4);
    half8 h, l;
    split8(v0, v1, h, l);
    *(half8*)(hi + (size_t)g * 8) = h;
    *(half8*)(lo + (size_t)g * 8) = l;
}

__global__ void presplit_w2t(const float* __restrict__ W2,
                             _Float16* __restrict__ hi, _Float16* __restrict__ lo) {
    int g = blockIdx.x * blockDim.x + threadIdx.x;
    if (g >= W2T_G) return;
    const int e  = g & 63;
    const int jo = g >> 6;
    const float* src = W2 + (size_t)e * JD + jo * 8;
    float4 v0 = *(const float4*)src;
    float4 v1 = *(const float4*)(src + 4);
    half8 h, l;
    split8(v0, v1, h, l);
    *(half8*)(hi + (size_t)g * 8) = h;
    *(half8*)(lo + (size_t)g * 8) = l;
}

// -------- main fused kernel --------
__global__ __launch_bounds__(NTH, 1)
void router_v7(const float* __restrict__ inp, const float* __restrict__ cnd,
               const _Float16* __restrict__ W1h, const _Float16* __restrict__ W1l,
               const _Float16* __restrict__ W2h, const _Float16* __restrict__ W2l,
               float* __restrict__ out_mask, float* __restrict__ out_topi,
               float* __restrict__ out_rp, float* __restrict__ out_probs)
{
    __shared__ __align__(16) char smem[LDS_TOTAL];

    const int tid  = threadIdx.x;
    const int lane = tid & 63;
    const int w    = tid >> 6;      // wave 0..7
    const int tg   = w >> 1;        // token group: rows tg*32..+31
    const int jg   = w & 1;         // j half: cols jg*64..+63
    const int l15  = lane & 15;
    const int lg   = lane >> 4;     // 0..3 (k-oct)
    const int t0   = blockIdx.x * BM;

    // wave-private H slab: [32][HS] halves, hi then lo
    _Float16* const sHh = (_Float16*)(smem + OFF_H + w * 4608);
    _Float16* const sHl = sHh + 1152;

    // A staging: thread -> (row, k-oct); B staging: wave -> (plane, k-oct slot)
    const int srow  = tid >> 2;
    const int sslot = tid & 3;
    const int bplane = w >> 2;      // 0=hi, 1=lo
    const int bslot  = w & 3;

    // frag byte offsets within a buffer (hi plane; lo plane = +8192)
    int aoffB[2], boffB[4];
    #pragma unroll
    for (int tf = 0; tf < 2; ++tf) aoffB[tf] = (lg*128 + tg*32 + tf*16 + l15) * 16;
    #pragma unroll
    for (int jf = 0; jf < 4; ++jf) boffB[jf] = (lg*128 + jg*64 + jf*16 + l15) * 16;

    const f32x4 vzero = {0.f, 0.f, 0.f, 0.f};
    f32x4 lacc[2][4];
    #pragma unroll
    for (int tf = 0; tf < 2; ++tf)
        #pragma unroll
        for (int ef = 0; ef < 4; ++ef) lacc[tf][ef] = vzero;

    const float* const xA = inp + (size_t)(t0 + srow) * D0;
    const float* const xC = cnd + (size_t)(t0 + srow) * DCC;
    const _Float16* const W1p = bplane ? W1l : W1h;

    for (int jc = 0; jc < NJC; ++jc) {
        f32x4 acc1[2][4];
        #pragma unroll
        for (int tf = 0; tf < 2; ++tf)
            #pragma unroll
            for (int jf = 0; jf < 4; ++jf) acc1[tf][jf] = vzero;

        // ---- prologue: stage k-step 0 into buf 0
        {
            // B: 2x global_load_lds per wave (128 rows of this wave's plane/slot)
            const _Float16* wsrc = W1p + ((size_t)(0*4 + bslot) * JD + jc*BJ) * 8;
            char* bb = smem + OFF_B + (bplane*512 + bslot*128) * 16;
            gload16(wsrc + (size_t)lane * 8, bb);
            gload16(wsrc + (size_t)(64 + lane) * 8, bb + 64*16);
            // A: load, split, write (k-step 0 is inp side)
            float4 ra0 = *(const float4*)(xA + sslot*8);
            float4 ra1 = *(const float4*)(xA + sslot*8 + 4);
            half8 hh, hl;
            split8(ra0, ra1, hh, hl);
            char* ab = smem + OFF_A;
            *(half8*)(ab + (sslot*128 + srow)*16) = hh;
            *(half8*)(ab + 8192 + (sslot*128 + srow)*16) = hl;
        }
        __syncthreads();

        int cur = 0;
        for (int ks = 0; ks < NKS; ++ks) {
            const bool more = (ks + 1 < NKS);
            const int nbuf = cur ^ 1;
            float4 ra0, ra1;
            if (more) {
                // issue x loads early (consumed after MFMAs)
                const int k = (ks + 1) * KC + sslot*8;
                const float* sA = (k < D0) ? (xA + k) : (xC + k - D0);
                ra0 = *(const float4*)sA;
                ra1 = *(const float4*)(sA + 4);
                // issue B global_load_lds into next buffer (non-blocking)
                const _Float16* wsrc = W1p + ((size_t)((ks+1)*4 + bslot) * JD + jc*BJ) * 8;
                char* bb = smem + OFF_B + nbuf*SZ_BUF + (bplane*512 + bslot*128) * 16;
                gload16(wsrc + (size_t)lane * 8, bb);
                gload16(wsrc + (size_t)(64 + lane) * 8, bb + 64*16);
            }
            // fragment reads from current buffer (conflict-free contiguous)
            const char* ab = smem + OFF_A + cur*SZ_BUF;
            const char* bb = smem + OFF_B + cur*SZ_BUF;
            half8 ah[2], al[2], bh[4], bl[4];
            #pragma unroll
            for (int tf = 0; tf < 2; ++tf) {
                ah[tf] = *(const half8*)(ab + aoffB[tf]);
                al[tf] = *(const half8*)(ab + 8192 + aoffB[tf]);
            }
            #pragma unroll
            for (int jf = 0; jf < 4; ++jf) {
                bh[jf] = *(const half8*)(bb + boffB[jf]);
                bl[jf] = *(const half8*)(bb + 8192 + boffB[jf]);
            }
            #pragma unroll
            for (int tf = 0; tf < 2; ++tf)
                #pragma unroll
                for (int jf = 0; jf < 4; ++jf) {
                    acc1[tf][jf] = mfma16(ah[tf], bh[jf], acc1[tf][jf]);
                    acc1[tf][jf] = mfma16(ah[tf], bl[jf], acc1[tf][jf]);
                    acc1[tf][jf] = mfma16(al[tf], bh[jf], acc1[tf][jf]);
                }
            if (more) {   // write-late: split waits on x loads here (counted vmcnt)
                half8 hh, hl;
                split8(ra0, ra1, hh, hl);
                char* nab = smem + OFF_A + nbuf*SZ_BUF;
                *(half8*)(nab + (sslot*128 + srow)*16) = hh;
                *(half8*)(nab + 8192 + (sslot*128 + srow)*16) = hl;
            }
            __syncthreads();   // single barrier: drains B gloads + A writes
            cur = nbuf;
        }

        // ---- GELU + GEMM2: two 32-col half-passes through wave-private H slab
        #pragma unroll
        for (int h2 = 0; h2 < 2; ++h2) {
            #pragma unroll
            for (int c = 0; c < 2; ++c) {
                const int jf = h2*2 + c;
                #pragma unroll
                for (int tf = 0; tf < 2; ++tf)
                    #pragma unroll
                    for (int r = 0; r < 4; ++r) {
                        const float v = acc1[tf][jf][r];
                        const float g = 0.5f * v * (1.0f + erff(v * 0.70710678118654752f));
                        const _Float16 gh = (_Float16)g;
                        const _Float16 gl = (_Float16)(g - (float)gh);
                        const int o = (tf*16 + lg*4 + r) * HS + c*16 + l15;
                        sHh[o] = gh; sHl[o] = gl;
                    }
            }
            // W2t granule base for this half-pass: j-octs (jc*16 + jg*8 + h2*4 + lg)
            const int joct0 = jc*16 + jg*8 + h2*4;
            half8 a2h[2], a2l[2];
            #pragma unroll
            for (int tf = 0; tf < 2; ++tf) {
                const int o = (tf*16 + l15) * HS + lg*8;
                a2h[tf] = *(const half8*)(sHh + o);
                a2l[tf] = *(const half8*)(sHl + o);
            }
            #pragma unroll
            for (int ef = 0; ef < 4; ++ef) {
                const size_t wg = ((size_t)(joct0 + lg) * 64 + ef*16 + l15) * 8;
                half8 b2h = *(const half8*)(W2h + wg);
                half8 b2l = *(const half8*)(W2l + wg);
                #pragma unroll
                for (int tf = 0; tf < 2; ++tf) {
                    lacc[tf][ef] = mfma16(a2h[tf], b2h, lacc[tf][ef]);
                    lacc[tf][ef] = mfma16(a2h[tf], b2l, lacc[tf][ef]);
                    lacc[tf][ef] = mfma16(a2l[tf], b2h, lacc[tf][ef]);
                }
            }
        }
    }

    // ---- epilogue: reduce jg halves into Lred, softmax + top-2, write outputs
    __syncthreads();
    float* const Lred = (float*)(smem + OFF_LRED);
    if (jg == 1) {
        #pragma unroll
        for (int tf = 0; tf < 2; ++tf)
            #pragma unroll
            for (int ef = 0; ef < 4; ++ef)
                #pragma unroll
                for (int r = 0; r < 4; ++r)
                    Lred[(tg*32 + tf*16 + lg*4 + r) * 68 + ef*16 + l15] = lacc[tf][ef][r];
    }
    __syncthreads();
    if (jg == 0) {
        #pragma unroll
        for (int tf = 0; tf < 2; ++tf)
            #pragma unroll
            for (int ef = 0; ef < 4; ++ef)
                #pragma unroll
                for (int r = 0; r < 4; ++r) {
                    const int o = (tg*32 + tf*16 + lg*4 + r) * 68 + ef*16 + l15;
                    Lred[o] += lacc[tf][ef][r];
                }
    }
    __syncthreads();

    float* const mA   = (float*)(smem + OFF_EPI);
    float* const invA = mA + BM;
    int*   const i1A  = (int*)(invA + BM);
    int*   const i2A  = i1A + BM;
    float* const rp1A = (float*)(i2A + BM);
    float* const rp2A = rp1A + BM;

    if (tid < BM) {
        const float* row = Lred + tid * 68;
        float m = -3.402823466e38f;
        for (int e = 0; e < NE; ++e) m = fmaxf(m, row[e]);
        float s = 0.f, v1 = -3.402823466e38f, v2 = -3.402823466e38f;
        int i1 = 0, i2 = 0;
        for (int e = 0; e < NE; ++e) {
            const float v = row[e];
            s += expf(v - m);
            if (v > v1)      { v2 = v1; i2 = i1; v1 = v; i1 = e; }
            else if (v > v2) { v2 = v; i2 = e; }
        }
        const float inv = 1.f / s;
        const float p1 = fminf(expf(v1 - m) * inv + EPSV, 1.f - EPSV);
        const float p2 = fminf(expf(v2 - m) * inv + EPSV, 1.f - EPSV);
        mA[tid] = m; invA[tid] = inv; i1A[tid] = i1; i2A[tid] = i2;
        const float den = p1 + p2;
        rp1A[tid] = p1 / den; rp2A[tid] = p2 / den;
    }
    __syncthreads();

    for (int idx = tid; idx < BM * NE; idx += NTH) {
        const int r = idx >> 6, e = idx & 63;
        const size_t o = (size_t)(t0 + r) * NE + e;
        const float p = fminf(expf(Lred[r * 68 + e] - mA[r]) * invA[r] + EPSV, 1.f - EPSV);
        const int b1 = (e == i1A[r]), b2 = (e == i2A[r]);
        out_probs[o] = p;
        out_mask[o]  = (b1 | b2) ? 1.f : 0.f;
        out_rp[o]    = b1 ? rp1A[r] : (b2 ? rp2A[r] : 0.f);
    }
    if (tid < BM * 2) {
        const int r = tid >> 1, q = tid & 1;
        out_topi[(size_t)(t0 + r) * 2 + q] = (float)(q ? i2A[r] : i1A[r]);
    }
}

extern "C" void kernel_launch(void* const* d_in, const int* in_sizes, int n_in,
                              void* d_out, int out_size, void* d_ws, size_t ws_size,
                              hipStream_t stream) {
    const float* inp = (const float*)d_in[0];
    const float* cnd = (const float*)d_in[1];
    const float* W1  = (const float*)d_in[2];
    const float* W2  = (const float*)d_in[3];

    float* out = (float*)d_out;
    const size_t NT = (size_t)N_TOK;
    float* out_mask  = out;
    float* out_topi  = out + NT * NE;
    float* out_rp    = out + NT * NE + NT * 2;
    float* out_probs = out + NT * NE + NT * 2 + NT * NE;

    _Float16* W1h = (_Float16*)d_ws;                 // 192*3072*8 halves
    _Float16* W1l = W1h + (size_t)W1T_G * 8;
    _Float16* W2h = W1l + (size_t)W1T_G * 8;         // 384*64*8 halves
    _Float16* W2l = W2h + (size_t)W2T_G * 8;

    hipLaunchKernelGGL(presplit_w1t, dim3((W1T_G + 255) / 256), dim3(256), 0, stream, W1, W1h, W1l);
    hipLaunchKernelGGL(presplit_w2t, dim3((W2T_G + 255) / 256), dim3(256), 0, stream, W2, W2h, W2l);
    hipLaunchKernelGGL(router_v7, dim3(N_TOK / BM), dim3(NTH), 0, stream,
                       inp, cnd, W1h, W1l, W2h, W2l,
                       out_mask, out_topi, out_rp, out_probs);
}

// Round 8
// 1117.339 us; speedup vs baseline: 4.7588x; 1.1465x over previous
//
#include <hip/hip_runtime.h>
#include <cmath>

// RouterCond fused, round 8: BK=64 (2 k-steps per barrier -> latency window
// doubled, barriers halved), A/B double-buffered koct-granule LDS, XOR-swizzled
// A staging writes (conflict-free), H/Lred/epilogue aliased into dead buffers.
#define N_TOK 32768
#define D0    1024
#define DCC   512
#define DIN   1536
#define JD    3072
#define NE    64
#define BM    128
#define BJ    128
#define BK    64
#define NJC   (JD/BJ)      // 24
#define NIT   (DIN/BK)     // 24
#define NTH   512
#define HS    36           // H slab row stride in halves
#define EPSV  1e-9f

typedef _Float16 half8 __attribute__((ext_vector_type(8)));
typedef float    f32x4 __attribute__((ext_vector_type(4)));

// ---- LDS: granules of 16 B. Buffer = [plane(2)][koct(8)][row(128)] granules.
#define SZ_BUF 32768
#define OFF_A  0                       // A bufs: 0, 32768
#define OFF_B  65536                   // B bufs: 65536, 98304
#define LDS_TOTAL 131072
#define OFF_H    0                     // GEMM2 H slabs alias dead A (8*4608=36864)
#define OFF_LRED 65536                 // epilogue aliases dead B ([128][68] f32)
#define OFF_EPI  (65536 + 34816)

// ---- workspace: pre-split + pre-transposed fp16 planes (granule = 8 halves)
// W1t[ko][j]: granule = W1[j][ko*8..+8), ko in [0,192), j in [0,3072)
// W2t[jo][e]: granule = W2[e][jo*8..+8), jo in [0,384),  e in [0,64)
#define W1T_G (192*3072)
#define W2T_G (384*64)

__device__ __forceinline__ f32x4 mfma16(half8 a, half8 b, f32x4 c) {
    return __builtin_amdgcn_mfma_f32_16x16x32_f16(a, b, c, 0, 0, 0);
}

__device__ __forceinline__ void split8(const float4 v0, const float4 v1, half8& hh, half8& hl) {
    float f[8] = {v0.x, v0.y, v0.z, v0.w, v1.x, v1.y, v1.z, v1.w};
    #pragma unroll
    for (int i = 0; i < 8; ++i) {
        _Float16 h = (_Float16)f[i];
        hh[i] = h;
        hl[i] = (_Float16)(f[i] - (float)h);
    }
}

__device__ __forceinline__ void gload16(const void* g, void* l) {
    __builtin_amdgcn_global_load_lds(
        (const __attribute__((address_space(1))) unsigned int*)g,
        (__attribute__((address_space(3))) unsigned int*)l, 16, 0, 0);
}

// -------- prologue kernels (unchanged from r7, proven) --------
__global__ void presplit_w1t(const float* __restrict__ W1,
                             _Float16* __restrict__ hi, _Float16* __restrict__ lo) {
    int g = blockIdx.x * blockDim.x + threadIdx.x;
    if (g >= W1T_G) return;
    const int j  = g % JD;
    const int ko = g / JD;
    const float* src = W1 + (size_t)j * DIN + ko * 8;
    float4 v0 = *(const float4*)src;
    float4 v1 = *(const float4*)(src + 4);
    half8 h, l;
    split8(v0, v1, h, l);
    *(half8*)(hi + (size_t)g * 8) = h;
    *(half8*)(lo + (size_t)g * 8) = l;
}

__global__ void presplit_w2t(const float* __restrict__ W2,
                             _Float16* __restrict__ hi, _Float16* __restrict__ lo) {
    int g = blockIdx.x * blockDim.x + threadIdx.x;
    if (g >= W2T_G) return;
    const int e  = g & 63;
    const int jo = g >> 6;
    const float* src = W2 + (size_t)e * JD + jo * 8;
    float4 v0 = *(const float4*)src;
    float4 v1 = *(const float4*)(src + 4);
    half8 h, l;
    split8(v0, v1, h, l);
    *(half8*)(hi + (size_t)g * 8) = h;
    *(half8*)(lo + (size_t)g * 8) = l;
}

// -------- main fused kernel --------
__global__ __launch_bounds__(NTH, 1)
void router_v8(const float* __restrict__ inp, const float* __restrict__ cnd,
               const _Float16* __restrict__ W1h, const _Float16* __restrict__ W1l,
               const _Float16* __restrict__ W2h, const _Float16* __restrict__ W2l,
               float* __restrict__ out_mask, float* __restrict__ out_topi,
               float* __restrict__ out_rp, float* __restrict__ out_probs)
{
    __shared__ __align__(16) char smem[LDS_TOTAL];

    const int tid  = threadIdx.x;
    const int lane = tid & 63;
    const int w    = tid >> 6;      // wave 0..7
    const int tg   = w >> 1;        // token group: rows tg*32..+31
    const int jg   = w & 1;         // j half: cols jg*64..+63
    const int l15  = lane & 15;
    const int lg   = lane >> 4;     // 0..3
    const int t0   = blockIdx.x * BM;

    // GEMM2 wave-private H slab (aliases dead A region)
    _Float16* const sHh = (_Float16*)(smem + OFF_H + w * 4608);
    _Float16* const sHl = sHh + 1152;

    // A staging mapping: thread -> (row, koct pair)
    const int arow  = tid >> 2;        // 0..127
    const int aslot = tid & 3;         // kocts aslot*2, aslot*2+1

    // B staging mapping (wave-uniform): plane, koct pair
    const int bplane = w & 1;
    const int bk0    = (w >> 1) * 2;   // kocts bk0, bk0+1

    const f32x4 vzero = {0.f, 0.f, 0.f, 0.f};
    f32x4 lacc[2][4];
    #pragma unroll
    for (int tf = 0; tf < 2; ++tf)
        #pragma unroll
        for (int ef = 0; ef < 4; ++ef) lacc[tf][ef] = vzero;

    const float* const xA = inp + (size_t)(t0 + arow) * D0;
    const float* const xC = cnd + (size_t)(t0 + arow) * DCC;
    const _Float16* const Wbp = bplane ? W1l : W1h;

    for (int jc = 0; jc < NJC; ++jc) {
        f32x4 acc1[2][4];
        #pragma unroll
        for (int tf = 0; tf < 2; ++tf)
            #pragma unroll
            for (int jf = 0; jf < 4; ++jf) acc1[tf][jf] = vzero;

        // ---- stage iter 0 into buf 0
        {
            #pragma unroll
            for (int q = 0; q < 2; ++q) {      // B: 4 gloads/wave
                const int ko = bk0 + q;        // it=0
                const _Float16* src = Wbp + ((size_t)ko * JD + jc * BJ) * 8;
                char* dst = smem + OFF_B + ((bplane * 8 + ko) * 128) * 16;
                gload16(src + (size_t)lane * 8, dst);
                gload16(src + (size_t)(64 + lane) * 8, dst + 1024);
            }
            #pragma unroll
            for (int q2 = 0; q2 < 2; ++q2) {   // A: load+split+swizzled write
                const int koct = aslot * 2 + q2;
                const int k = koct * 8;        // it=0
                const float* sx = (k < D0) ? (xA + k) : (xC + k - D0);
                float4 v0 = *(const float4*)sx;
                float4 v1 = *(const float4*)(sx + 4);
                half8 hh, hl;
                split8(v0, v1, hh, hl);
                const int g = koct * 128 + (arow ^ (koct & 7));
                *(half8*)(smem + OFF_A + g * 16) = hh;
                *(half8*)(smem + OFF_A + (1024 + g) * 16) = hl;
            }
        }
        __syncthreads();

        for (int it = 0; it < NIT; ++it) {
            const int cur = it & 1, nxt = cur ^ 1;
            const bool more = (it + 1 < NIT);
            float4 xv[4];
            if (more) {
                // issue next-iter B gloads FIRST (longest latency)
                #pragma unroll
                for (int q = 0; q < 2; ++q) {
                    const int ko = (it + 1) * 8 + bk0 + q;
                    const _Float16* src = Wbp + ((size_t)ko * JD + jc * BJ) * 8;
                    char* dst = smem + OFF_B + nxt * SZ_BUF + ((bplane * 8 + bk0 + q) * 128) * 16;
                    gload16(src + (size_t)lane * 8, dst);
                    gload16(src + (size_t)(64 + lane) * 8, dst + 1024);
                }
                // issue next-iter x loads
                #pragma unroll
                for (int q2 = 0; q2 < 2; ++q2) {
                    const int k = (it + 1) * BK + (aslot * 2 + q2) * 8;
                    const float* sx = (k < D0) ? (xA + k) : (xC + k - D0);
                    xv[q2 * 2]     = *(const float4*)sx;
                    xv[q2 * 2 + 1] = *(const float4*)(sx + 4);
                }
            }
            // compute 2 half-steps from current buffers
            const char* ab = smem + OFF_A + cur * SZ_BUF;
            const char* bb = smem + OFF_B + cur * SZ_BUF;
            #pragma unroll
            for (int ks2 = 0; ks2 < 2; ++ks2) {
                const int c = ks2 * 4 + lg;
                half8 ah[2], al[2], bh[4], bl[4];
                #pragma unroll
                for (int tf = 0; tf < 2; ++tf) {
                    const int g = c * 128 + ((tg * 32 + tf * 16 + l15) ^ c);
                    ah[tf] = *(const half8*)(ab + g * 16);
                    al[tf] = *(const half8*)(ab + (1024 + g) * 16);
                }
                #pragma unroll
                for (int jf = 0; jf < 4; ++jf) {
                    const int g = c * 128 + (jg * 64 + jf * 16 + l15);
                    bh[jf] = *(const half8*)(bb + g * 16);
                    bl[jf] = *(const half8*)(bb + (1024 + g) * 16);
                }
                #pragma unroll
                for (int tf = 0; tf < 2; ++tf)
                    #pragma unroll
                    for (int jf = 0; jf < 4; ++jf) {
                        acc1[tf][jf] = mfma16(ah[tf], bh[jf], acc1[tf][jf]);
                        acc1[tf][jf] = mfma16(ah[tf], bl[jf], acc1[tf][jf]);
                        acc1[tf][jf] = mfma16(al[tf], bh[jf], acc1[tf][jf]);
                    }
            }
            if (more) {   // split + swizzled write into next A buffer
                char* nab = smem + OFF_A + nxt * SZ_BUF;
                #pragma unroll
                for (int q2 = 0; q2 < 2; ++q2) {
                    const int koct = aslot * 2 + q2;
                    half8 hh, hl;
                    split8(xv[q2 * 2], xv[q2 * 2 + 1], hh, hl);
                    const int g = koct * 128 + (arow ^ (koct & 7));
                    *(half8*)(nab + g * 16) = hh;
                    *(half8*)(nab + (1024 + g) * 16) = hl;
                }
            }
            __syncthreads();   // one barrier per 2 k-steps
        }

        // ---- GELU + GEMM2 (r7-proven), H slab aliases dead A region
        #pragma unroll
        for (int h2 = 0; h2 < 2; ++h2) {
            #pragma unroll
            for (int c = 0; c < 2; ++c) {
                const int jf = h2 * 2 + c;
                #pragma unroll
                for (int tf = 0; tf < 2; ++tf)
                    #pragma unroll
                    for (int r = 0; r < 4; ++r) {
                        const float v = acc1[tf][jf][r];
                        const float g = 0.5f * v * (1.0f + erff(v * 0.70710678118654752f));
                        const _Float16 gh = (_Float16)g;
                        const _Float16 gl = (_Float16)(g - (float)gh);
                        const int o = (tf * 16 + lg * 4 + r) * HS + c * 16 + l15;
                        sHh[o] = gh; sHl[o] = gl;
                    }
            }
            const int joct0 = jc * 16 + jg * 8 + h2 * 4;
            half8 a2h[2], a2l[2];
            #pragma unroll
            for (int tf = 0; tf < 2; ++tf) {
                const int o = (tf * 16 + l15) * HS + lg * 8;
                a2h[tf] = *(const half8*)(sHh + o);
                a2l[tf] = *(const half8*)(sHl + o);
            }
            #pragma unroll
            for (int ef = 0; ef < 4; ++ef) {
                const size_t wg = ((size_t)(joct0 + lg) * 64 + ef * 16 + l15) * 8;
                half8 b2h = *(const half8*)(W2h + wg);
                half8 b2l = *(const half8*)(W2l + wg);
                #pragma unroll
                for (int tf = 0; tf < 2; ++tf) {
                    lacc[tf][ef] = mfma16(a2h[tf], b2h, lacc[tf][ef]);
                    lacc[tf][ef] = mfma16(a2h[tf], b2l, lacc[tf][ef]);
                    lacc[tf][ef] = mfma16(a2l[tf], b2h, lacc[tf][ef]);
                }
            }
        }
        __syncthreads();   // H reads done before next jc overwrites A region
    }

    // ---- epilogue: reduce jg halves into Lred (aliases dead B), softmax+top2
    float* const Lred = (float*)(smem + OFF_LRED);
    if (jg == 1) {
        #pragma unroll
        for (int tf = 0; tf < 2; ++tf)
            #pragma unroll
            for (int ef = 0; ef < 4; ++ef)
                #pragma unroll
                for (int r = 0; r < 4; ++r)
                    Lred[(tg*32 + tf*16 + lg*4 + r) * 68 + ef*16 + l15] = lacc[tf][ef][r];
    }
    __syncthreads();
    if (jg == 0) {
        #pragma unroll
        for (int tf = 0; tf < 2; ++tf)
            #pragma unroll
            for (int ef = 0; ef < 4; ++ef)
                #pragma unroll
                for (int r = 0; r < 4; ++r) {
                    const int o = (tg*32 + tf*16 + lg*4 + r) * 68 + ef*16 + l15;
                    Lred[o] += lacc[tf][ef][r];
                }
    }
    __syncthreads();

    float* const mA   = (float*)(smem + OFF_EPI);
    float* const invA = mA + BM;
    int*   const i1A  = (int*)(invA + BM);
    int*   const i2A  = i1A + BM;
    float* const rp1A = (float*)(i2A + BM);
    float* const rp2A = rp1A + BM;

    if (tid < BM) {
        const float* row = Lred + tid * 68;
        float m = -3.402823466e38f;
        for (int e = 0; e < NE; ++e) m = fmaxf(m, row[e]);
        float s = 0.f, v1 = -3.402823466e38f, v2 = -3.402823466e38f;
        int i1 = 0, i2 = 0;
        for (int e = 0; e < NE; ++e) {
            const float v = row[e];
            s += expf(v - m);
            if (v > v1)      { v2 = v1; i2 = i1; v1 = v; i1 = e; }
            else if (v > v2) { v2 = v; i2 = e; }
        }
        const float inv = 1.f / s;
        const float p1 = fminf(expf(v1 - m) * inv + EPSV, 1.f - EPSV);
        const float p2 = fminf(expf(v2 - m) * inv + EPSV, 1.f - EPSV);
        mA[tid] = m; invA[tid] = inv; i1A[tid] = i1; i2A[tid] = i2;
        const float den = p1 + p2;
        rp1A[tid] = p1 / den; rp2A[tid] = p2 / den;
    }
    __syncthreads();

    for (int idx = tid; idx < BM * NE; idx += NTH) {
        const int r = idx >> 6, e = idx & 63;
        const size_t o = (size_t)(t0 + r) * NE + e;
        const float p = fminf(expf(Lred[r * 68 + e] - mA[r]) * invA[r] + EPSV, 1.f - EPSV);
        const int b1 = (e == i1A[r]), b2 = (e == i2A[r]);
        out_probs[o] = p;
        out_mask[o]  = (b1 | b2) ? 1.f : 0.f;
        out_rp[o]    = b1 ? rp1A[r] : (b2 ? rp2A[r] : 0.f);
    }
    if (tid < BM * 2) {
        const int r = tid >> 1, q = tid & 1;
        out_topi[(size_t)(t0 + r) * 2 + q] = (float)(q ? i2A[r] : i1A[r]);
    }
}

extern "C" void kernel_launch(void* const* d_in, const int* in_sizes, int n_in,
                              void* d_out, int out_size, void* d_ws, size_t ws_size,
                              hipStream_t stream) {
    const float* inp = (const float*)d_in[0];
    const float* cnd = (const float*)d_in[1];
    const float* W1  = (const float*)d_in[2];
    const float* W2  = (const float*)d_in[3];

    float* out = (float*)d_out;
    const size_t NT = (size_t)N_TOK;
    float* out_mask  = out;
    float* out_topi  = out + NT * NE;
    float* out_rp    = out + NT * NE + NT * 2;
    float* out_probs = out + NT * NE + NT * 2 + NT * NE;

    _Float16* W1h = (_Float16*)d_ws;
    _Float16* W1l = W1h + (size_t)W1T_G * 8;
    _Float16* W2h = W1l + (size_t)W1T_G * 8;
    _Float16* W2l = W2h + (size_t)W2T_G * 8;

    hipLaunchKernelGGL(presplit_w1t, dim3((W1T_G + 255) / 256), dim3(256), 0, stream, W1, W1h, W1l);
    hipLaunchKernelGGL(presplit_w2t, dim3((W2T_G + 255) / 256), dim3(256), 0, stream, W2, W2h, W2l);
    hipLaunchKernelGGL(router_v8, dim3(N_TOK / BM), dim3(NTH), 0, stream,
                       inp, cnd, W1h, W1l, W2h, W2l,
                       out_mask, out_topi, out_rp, out_probs);
}

// Round 9
// 1097.550 us; speedup vs baseline: 4.8446x; 1.0180x over previous
//
#include <hip/hip_runtime.h>
#include <cmath>

// RouterCond fused, round 9: 64x64 wave tiles (BJ=256) cut LDS frag reads 1.5x,
// BK=32 koct-granule dbuf (conflict-free, no swizzle needed), B via global_load_lds
// prefetched one full iter ahead, expert-split GEMM2 (lacc 16 VGPR, no jg-reduce).
#define N_TOK 32768
#define D0    1024
#define DCC   512
#define DIN   1536
#define JD    3072
#define NE    64
#define BM    128
#define BJ    256
#define BK    32
#define NJC   (JD/BJ)      // 12
#define NIT   (DIN/BK)     // 48
#define NTH   512
#define HS    36
#define EPSV  1e-9f

typedef _Float16 half8 __attribute__((ext_vector_type(8)));
typedef float    f32x4 __attribute__((ext_vector_type(4)));

// ---- LDS: 16B granules. A buf = [plane(2)][koct(4)][row(128)] = 16KB.
//      B buf = [plane(2)][koct(4)][col(256)] = 32KB. Both double-buffered.
#define SZ_A  16384
#define SZ_B  32768
#define OFF_A 0                    // A bufs: 0, 16384
#define OFF_B 32768                // B bufs: 32768, 65536
#define LDS_TOTAL 98304
// GEMM2 H slabs (8 x 9216 = 73728) alias dead A/B, barrier-fenced.
#define OFF_H    0
// epilogue: Lred [128][68] f32 = 34816 at 0 (H dead); scalars after.
#define OFF_LRED 0
#define OFF_EPI  36864

// ---- workspace: pre-split + pre-transposed fp16 planes (granule = 8 halves)
#define W1T_G (192*3072)
#define W2T_G (384*64)

__device__ __forceinline__ f32x4 mfma16(half8 a, half8 b, f32x4 c) {
    return __builtin_amdgcn_mfma_f32_16x16x32_f16(a, b, c, 0, 0, 0);
}

__device__ __forceinline__ void split8(const float4 v0, const float4 v1, half8& hh, half8& hl) {
    float f[8] = {v0.x, v0.y, v0.z, v0.w, v1.x, v1.y, v1.z, v1.w};
    #pragma unroll
    for (int i = 0; i < 8; ++i) {
        _Float16 h = (_Float16)f[i];
        hh[i] = h;
        hl[i] = (_Float16)(f[i] - (float)h);
    }
}

__device__ __forceinline__ void gload16(const void* g, void* l) {
    __builtin_amdgcn_global_load_lds(
        (const __attribute__((address_space(1))) unsigned int*)g,
        (__attribute__((address_space(3))) unsigned int*)l, 16, 0, 0);
}

// -------- prologue kernels (r7/r8-proven) --------
__global__ void presplit_w1t(const float* __restrict__ W1,
                             _Float16* __restrict__ hi, _Float16* __restrict__ lo) {
    int g = blockIdx.x * blockDim.x + threadIdx.x;
    if (g >= W1T_G) return;
    const int j  = g % JD;
    const int ko = g / JD;
    const float* src = W1 + (size_t)j * DIN + ko * 8;
    float4 v0 = *(const float4*)src;
    float4 v1 = *(const float4*)(src + 4);
    half8 h, l;
    split8(v0, v1, h, l);
    *(half8*)(hi + (size_t)g * 8) = h;
    *(half8*)(lo + (size_t)g * 8) = l;
}

__global__ void presplit_w2t(const float* __restrict__ W2,
                             _Float16* __restrict__ hi, _Float16* __restrict__ lo) {
    int g = blockIdx.x * blockDim.x + threadIdx.x;
    if (g >= W2T_G) return;
    const int e  = g & 63;
    const int jo = g >> 6;
    const float* src = W2 + (size_t)e * JD + jo * 8;
    float4 v0 = *(const float4*)src;
    float4 v1 = *(const float4*)(src + 4);
    half8 h, l;
    split8(v0, v1, h, l);
    *(half8*)(hi + (size_t)g * 8) = h;
    *(half8*)(lo + (size_t)g * 8) = l;
}

// -------- main fused kernel --------
__global__ __launch_bounds__(NTH, 1)
void router_v9(const float* __restrict__ inp, const float* __restrict__ cnd,
               const _Float16* __restrict__ W1h, const _Float16* __restrict__ W1l,
               const _Float16* __restrict__ W2h, const _Float16* __restrict__ W2l,
               float* __restrict__ out_mask, float* __restrict__ out_topi,
               float* __restrict__ out_rp, float* __restrict__ out_probs)
{
    __shared__ __align__(16) char smem[LDS_TOTAL];

    const int tid  = threadIdx.x;
    const int lane = tid & 63;
    const int w    = tid >> 6;      // wave 0..7
    const int tg   = w >> 2;        // token half: rows tg*64..+63
    const int jg   = w & 3;         // j quarter (64 cols) / expert group (16)
    const int l15  = lane & 15;
    const int lg   = lane >> 4;     // 0..3 = k-oct
    const int t0   = blockIdx.x * BM;

    // A staging: wave -> k-oct (w>>1), lanes -> consecutive rows (conflict-free)
    const int akoct = w >> 1;                 // 0..3
    const int arow  = (w & 1) * 64 + lane;    // 0..127
    // B staging: wave -> (plane, koct); 4 gload16 of 64 cols each
    const int bplane = w >> 2;                // 0..1
    const int bkoct  = w & 3;                 // 0..3

    // frag byte offsets within a buffer (hi plane; lo at +8192 A / +16384 B)
    int aoff[4], boff[4];
    #pragma unroll
    for (int tf = 0; tf < 4; ++tf) aoff[tf] = (lg*128 + tg*64 + tf*16 + l15) * 16;
    #pragma unroll
    for (int jf = 0; jf < 4; ++jf) boff[jf] = (lg*256 + jg*64 + jf*16 + l15) * 16;

    const f32x4 vzero = {0.f, 0.f, 0.f, 0.f};
    f32x4 lacc[4] = {vzero, vzero, vzero, vzero};   // 64 tokens x 16 experts (final)

    const float* const xrowA = inp + (size_t)(t0 + arow) * D0;
    const float* const xrowC = cnd + (size_t)(t0 + arow) * DCC;
    const _Float16* const Wbp = bplane ? W1l : W1h;

    // wave-private H slab: [64 tok][HS] halves, hi then lo (2304 halves each)
    _Float16* const myHh = (_Float16*)(smem + OFF_H + w * 9216);
    _Float16* const myHl = myHh + 2304;

    for (int jc = 0; jc < NJC; ++jc) {
        f32x4 acc1[4][4];
        #pragma unroll
        for (int tf = 0; tf < 4; ++tf)
            #pragma unroll
            for (int jf = 0; jf < 4; ++jf) acc1[tf][jf] = vzero;

        // ---- prologue: stage it=0 into buf 0
        {
            #pragma unroll
            for (int q = 0; q < 4; ++q) {
                const _Float16* src = Wbp + ((size_t)bkoct * JD + jc*BJ + q*64 + lane) * 8;
                char* dst = smem + OFF_B + bplane*16384 + bkoct*4096 + q*1024;
                gload16(src, dst);
            }
            const float* sx = xrowA + akoct * 8;         // it=0 always inp side
            float4 v0 = *(const float4*)sx;
            float4 v1 = *(const float4*)(sx + 4);
            half8 hh, hl;
            split8(v0, v1, hh, hl);
            const int g = (akoct*128 + arow) * 16;
            *(half8*)(smem + OFF_A + g) = hh;
            *(half8*)(smem + OFF_A + 8192 + g) = hl;
        }
        __syncthreads();

        for (int it = 0; it < NIT; ++it) {
            const int cur = it & 1, nxt = cur ^ 1;
            const bool more = (it + 1 < NIT);
            float4 xv0, xv1;
            if (more) {
                // issue next-iter B gloads into nxt buffer (longest latency first)
                const int ko = (it + 1) * 4 + bkoct;
                #pragma unroll
                for (int q = 0; q < 4; ++q) {
                    const _Float16* src = Wbp + ((size_t)ko * JD + jc*BJ + q*64 + lane) * 8;
                    char* dst = smem + OFF_B + nxt*SZ_B + bplane*16384 + bkoct*4096 + q*1024;
                    gload16(src, dst);
                }
                // issue next-iter x load (wave-uniform side selection)
                const int k = (it + 1) * BK + akoct * 8;
                const float* sx = (k < D0) ? (xrowA + k) : (xrowC + k - D0);
                xv0 = *(const float4*)sx;
                xv1 = *(const float4*)(sx + 4);
            }
            // fragment reads (contiguous-16-granule, conflict-free)
            const char* ab = smem + OFF_A + cur*SZ_A;
            const char* bb = smem + OFF_B + cur*SZ_B;
            half8 ah[4], al[4], bh[4], bl[4];
            #pragma unroll
            for (int tf = 0; tf < 4; ++tf) {
                ah[tf] = *(const half8*)(ab + aoff[tf]);
                al[tf] = *(const half8*)(ab + 8192 + aoff[tf]);
            }
            #pragma unroll
            for (int jf = 0; jf < 4; ++jf) {
                bh[jf] = *(const half8*)(bb + boff[jf]);
                bl[jf] = *(const half8*)(bb + 16384 + boff[jf]);
            }
            #pragma unroll
            for (int tf = 0; tf < 4; ++tf)
                #pragma unroll
                for (int jf = 0; jf < 4; ++jf) {
                    acc1[tf][jf] = mfma16(ah[tf], bh[jf], acc1[tf][jf]);
                    acc1[tf][jf] = mfma16(ah[tf], bl[jf], acc1[tf][jf]);
                    acc1[tf][jf] = mfma16(al[tf], bh[jf], acc1[tf][jf]);
                }
            if (more) {   // write-late A into nxt buffer
                half8 hh, hl;
                split8(xv0, xv1, hh, hl);
                const int g = (akoct*128 + arow) * 16;
                *(half8*)(smem + OFF_A + nxt*SZ_A + g) = hh;
                *(half8*)(smem + OFF_A + nxt*SZ_A + 8192 + g) = hl;
            }
            __syncthreads();   // one barrier per iter; gloads span the full iter
        }

        // ---- expert-split GEMM2: 2 rounds of 32-j chunks; each wave computes
        //      its 64 tokens x 16 experts reading all 4 sibling H slabs.
        #pragma unroll
        for (int r = 0; r < 2; ++r) {
            // GELU + split -> own slab chunk (H aliases dead A/B, post-k-loop)
            #pragma unroll
            for (int c = 0; c < 2; ++c) {
                const int jf = 2*r + c;
                #pragma unroll
                for (int tf = 0; tf < 4; ++tf)
                    #pragma unroll
                    for (int rr = 0; rr < 4; ++rr) {
                        const float v = acc1[tf][jf][rr];
                        const float gv = 0.5f * v * (1.0f + erff(v * 0.70710678118654752f));
                        const _Float16 gh = (_Float16)gv;
                        const _Float16 gl = (_Float16)(gv - (float)gh);
                        const int o = (tf*16 + lg*4 + rr) * HS + c*16 + l15;
                        myHh[o] = gh; myHl[o] = gl;
                    }
            }
            __syncthreads();   // all slabs' chunk-r visible
            #pragma unroll
            for (int s = 0; s < 4; ++s) {
                const _Float16* sh = (const _Float16*)(smem + OFF_H + (tg*4 + s) * 9216);
                const _Float16* sl = sh + 2304;
                const int jo = jc*32 + s*8 + r*4 + lg;
                const size_t wg = ((size_t)jo * 64 + jg*16 + l15) * 8;
                half8 b2h = *(const half8*)(W2h + wg);
                half8 b2l = *(const half8*)(W2l + wg);
                #pragma unroll
                for (int tf = 0; tf < 4; ++tf) {
                    const int o = (tf*16 + l15) * HS + lg*8;
                    half8 a2h = *(const half8*)(sh + o);
                    half8 a2l = *(const half8*)(sl + o);
                    lacc[tf] = mfma16(a2h, b2h, lacc[tf]);
                    lacc[tf] = mfma16(a2h, b2l, lacc[tf]);
                    lacc[tf] = mfma16(a2l, b2h, lacc[tf]);
                }
            }
            __syncthreads();   // chunk reads done before rewrite / restage
        }
    }

    // ---- epilogue: each wave owns final 64tok x 16exp -> Lred once, softmax, out
    float* const Lred = (float*)(smem + OFF_LRED);
    #pragma unroll
    for (int tf = 0; tf < 4; ++tf)
        #pragma unroll
        for (int rr = 0; rr < 4; ++rr)
            Lred[(tg*64 + tf*16 + lg*4 + rr) * 68 + jg*16 + l15] = lacc[tf][rr];
    __syncthreads();

    float* const mA   = (float*)(smem + OFF_EPI);
    float* const invA = mA + BM;
    int*   const i1A  = (int*)(invA + BM);
    int*   const i2A  = i1A + BM;
    float* const rp1A = (float*)(i2A + BM);
    float* const rp2A = rp1A + BM;

    if (tid < BM) {
        const float* row = Lred + tid * 68;
        float m = -3.402823466e38f;
        for (int e = 0; e < NE; ++e) m = fmaxf(m, row[e]);
        float s = 0.f, v1 = -3.402823466e38f, v2 = -3.402823466e38f;
        int i1 = 0, i2 = 0;
        for (int e = 0; e < NE; ++e) {
            const float v = row[e];
            s += expf(v - m);
            if (v > v1)      { v2 = v1; i2 = i1; v1 = v; i1 = e; }
            else if (v > v2) { v2 = v; i2 = e; }
        }
        const float inv = 1.f / s;
        const float p1 = fminf(expf(v1 - m) * inv + EPSV, 1.f - EPSV);
        const float p2 = fminf(expf(v2 - m) * inv + EPSV, 1.f - EPSV);
        mA[tid] = m; invA[tid] = inv; i1A[tid] = i1; i2A[tid] = i2;
        const float den = p1 + p2;
        rp1A[tid] = p1 / den; rp2A[tid] = p2 / den;
    }
    __syncthreads();

    for (int idx = tid; idx < BM * NE; idx += NTH) {
        const int r = idx >> 6, e = idx & 63;
        const size_t o = (size_t)(t0 + r) * NE + e;
        const float p = fminf(expf(Lred[r * 68 + e] - mA[r]) * invA[r] + EPSV, 1.f - EPSV);
        const int b1 = (e == i1A[r]), b2 = (e == i2A[r]);
        out_probs[o] = p;
        out_mask[o]  = (b1 | b2) ? 1.f : 0.f;
        out_rp[o]    = b1 ? rp1A[r] : (b2 ? rp2A[r] : 0.f);
    }
    if (tid < BM * 2) {
        const int r = tid >> 1, q = tid & 1;
        out_topi[(size_t)(t0 + r) * 2 + q] = (float)(q ? i2A[r] : i1A[r]);
    }
}

extern "C" void kernel_launch(void* const* d_in, const int* in_sizes, int n_in,
                              void* d_out, int out_size, void* d_ws, size_t ws_size,
                              hipStream_t stream) {
    const float* inp = (const float*)d_in[0];
    const float* cnd = (const float*)d_in[1];
    const float* W1  = (const float*)d_in[2];
    const float* W2  = (const float*)d_in[3];

    float* out = (float*)d_out;
    const size_t NT = (size_t)N_TOK;
    float* out_mask  = out;
    float* out_topi  = out + NT * NE;
    float* out_rp    = out + NT * NE + NT * 2;
    float* out_probs = out + NT * NE + NT * 2 + NT * NE;

    _Float16* W1h = (_Float16*)d_ws;
    _Float16* W1l = W1h + (size_t)W1T_G * 8;
    _Float16* W2h = W1l + (size_t)W1T_G * 8;
    _Float16* W2l = W2h + (size_t)W2T_G * 8;

    hipLaunchKernelGGL(presplit_w1t, dim3((W1T_G + 255) / 256), dim3(256), 0, stream, W1, W1h, W1l);
    hipLaunchKernelGGL(presplit_w2t, dim3((W2T_G + 255) / 256), dim3(256), 0, stream, W2, W2h, W2l);
    hipLaunchKernelGGL(router_v9, dim3(N_TOK / BM), dim3(NTH), 0, stream,
                       inp, cnd, W1h, W1l, W2h, W2l,
                       out_mask, out_topi, out_rp, out_probs);
}